// Round 4
// baseline (321.085 us; speedup 1.0000x reference)
//
#include <hip/hip_runtime.h>

// ScaledAttention B=8,T=2048,D=1024 single-head, SCALE=1/8.
// cvt f32->f16 -> fused QKV proj -> causal QK^T (compact f32 S) -> row softmax
// -> PV. GEMM core: 256x256 tile, BK=32 subtiles [256][32] f16 in a 4-deep
// LDS ring (8x16KB), 2 phases/tile, B-frags held in regs across phases,
// counted vmcnt(8) (never 0 mid-loop), setprio around MFMA clusters.

typedef float f32x4 __attribute__((ext_vector_type(4)));
typedef _Float16 half8 __attribute__((ext_vector_type(8)));

#define DEVINL __device__ __forceinline__
static constexpr float ATT_SCALE = 0.125f;  // 1/sqrt(1024/16)

DEVINL void gload_lds16(const _Float16* g, _Float16* l) {
  __builtin_amdgcn_global_load_lds((const __attribute__((address_space(1))) void*)g,
                                   (__attribute__((address_space(3))) void*)l, 16, 0, 0);
}

// Stage one [256 rows][32 k] f16 subtile (16KB). chunk c: row c>>2, kcol (c&3)*8.
DEVINL void stage_sub(const _Float16* __restrict__ g0, int ld, _Float16* slot, int tid) {
  const int w = tid >> 6;
  gload_lds16(g0 + (size_t)(tid >> 2) * ld + (tid & 3) * 8, slot + w * 512);
  gload_lds16(g0 + (size_t)((tid >> 2) + 128) * ld + (tid & 3) * 8, slot + 4096 + w * 512);
}

// 256x256 tile, 8 waves (2M x 4N), per-wave 128x64 = acc[8][4] (acc[ih*4+i]).
// Row of acc[ai][j] reg r = wm*128 + (ai>>2)*64 + (ai&3)*16 + lk*4 + r.
// Col = wn*64 + j*16 + lr.  NT >= 4.
template <class GA, class GB>
DEVINL void gemm_core(GA ga, GB gb, int lda, int ldb, int NT,
                      _Float16* lds, int tid, f32x4 acc[8][4]) {
  const int l = tid & 63, w = tid >> 6;
  const int wm = w >> 2, wn = w & 3;
  const int lr = l & 15, lk = l >> 4;
  const int aoff = (wm * 128 + lr) * 32 + lk * 8;
  const int boff = (wn * 64 + lr) * 32 + lk * 8;
  _Float16* const As = lds;           // 4 slots x 8192 f16
  _Float16* const Bs = lds + 32768;   // 4 slots x 8192 f16
  stage_sub(ga(0), lda, As, tid);
  stage_sub(gb(0), ldb, Bs, tid);
  stage_sub(ga(1), lda, As + 8192, tid);
  stage_sub(gb(1), ldb, Bs + 8192, tid);
  stage_sub(ga(2), lda, As + 16384, tid);
  stage_sub(gb(2), ldb, Bs + 16384, tid);
  asm volatile("s_waitcnt vmcnt(8)" ::: "memory");  // tile0 landed
  __builtin_amdgcn_s_barrier();
  half8 a[4], b[4];
  for (int t = 0; t < NT; ++t) {
    _Float16* Asl = As + (t & 3) * 8192;
    _Float16* Bsl = Bs + (t & 3) * 8192;
    const bool st = (t + 3 < NT);
    // phase ih0: read B-frags (held across both phases) + A-quadrant 0
#pragma unroll
    for (int j = 0; j < 4; ++j) b[j] = *(const half8*)&Bsl[boff + j * 512];
#pragma unroll
    for (int i = 0; i < 4; ++i) a[i] = *(const half8*)&Asl[aoff + i * 512];
    if (st) stage_sub(ga(t + 3), lda, As + ((t + 3) & 3) * 8192, tid);
    __builtin_amdgcn_s_barrier();
    asm volatile("s_waitcnt lgkmcnt(0)" ::: "memory");
    __builtin_amdgcn_sched_barrier(0);
    __builtin_amdgcn_s_setprio(1);
#pragma unroll
    for (int i = 0; i < 4; ++i)
#pragma unroll
      for (int j = 0; j < 4; ++j)
        acc[i][j] = __builtin_amdgcn_mfma_f32_16x16x32_f16(a[i], b[j], acc[i][j], 0, 0, 0);
    __builtin_amdgcn_s_setprio(0);
    __builtin_amdgcn_s_barrier();
    // phase ih1: A-quadrant 1, reuse b[]
#pragma unroll
    for (int i = 0; i < 4; ++i) a[i] = *(const half8*)&Asl[aoff + 2048 + i * 512];
    if (st) stage_sub(gb(t + 3), ldb, Bs + ((t + 3) & 3) * 8192, tid);
    __builtin_amdgcn_s_barrier();
    asm volatile("s_waitcnt lgkmcnt(0)" ::: "memory");
    __builtin_amdgcn_sched_barrier(0);
    __builtin_amdgcn_s_setprio(1);
#pragma unroll
    for (int i = 0; i < 4; ++i)
#pragma unroll
      for (int j = 0; j < 4; ++j)
        acc[4 + i][j] =
            __builtin_amdgcn_mfma_f32_16x16x32_f16(a[i], b[j], acc[4 + i][j], 0, 0, 0);
    __builtin_amdgcn_s_setprio(0);
    // end-of-tile: ensure tile t+1 resident; keep 2 tiles (8 loads) in flight
    if (t + 3 < NT)      { asm volatile("s_waitcnt vmcnt(8)" ::: "memory"); }
    else if (t + 2 < NT) { asm volatile("s_waitcnt vmcnt(4)" ::: "memory"); }
    else                 { asm volatile("s_waitcnt vmcnt(0)" ::: "memory"); }
    __builtin_amdgcn_s_barrier();
  }
}

__global__ __launch_bounds__(256) void cvt_f32_f16(const float* __restrict__ in,
                                                   _Float16* __restrict__ out, int n8) {
  int i = blockIdx.x * 256 + threadIdx.x;
  if (i >= n8) return;
  const float4* p = (const float4*)in + (size_t)i * 2;
  float4 v0 = p[0], v1 = p[1];
  half8 h;
  h[0] = (_Float16)v0.x; h[1] = (_Float16)v0.y; h[2] = (_Float16)v0.z; h[3] = (_Float16)v0.w;
  h[4] = (_Float16)v1.x; h[5] = (_Float16)v1.y; h[6] = (_Float16)v1.z; h[7] = (_Float16)v1.w;
  *((half8*)out + i) = h;
}

// Fused QKV: C[m,n]=sum_k x[m,k]W[n,k]+b[n], M=16384, N=3072, K=1024.
// Epilogue through LDS (rotated layout) for coalesced 16B stores.
__global__ __launch_bounds__(512, 2) void gemm_qkv(
    const _Float16* __restrict__ xh, const _Float16* __restrict__ Wqh,
    const _Float16* __restrict__ Wkh, const _Float16* __restrict__ Wvh,
    const float* __restrict__ bq, const float* __restrict__ bk,
    const float* __restrict__ bv, _Float16* __restrict__ Qh,
    _Float16* __restrict__ Kh, _Float16* __restrict__ VT) {
  __shared__ _Float16 lds[65536];
  const int tid = threadIdx.x;
  const int bid = blockIdx.x;
  const int swz = (bid & 7) * 96 + (bid >> 3);  // XCD swizzle, 768%8==0
  const int mt = swz / 12, nt = swz % 12;
  const int sel = nt >> 2;
  const _Float16* Wsel = sel == 0 ? Wqh : (sel == 1 ? Wkh : Wvh);
  const float* bsel = sel == 0 ? bq : (sel == 1 ? bk : bv);
  const _Float16* Ab = xh + (size_t)mt * 256 * 1024;
  const _Float16* Bb = Wsel + (size_t)(nt & 3) * 256 * 1024;
  f32x4 acc[8][4] = {};
  auto ga = [&](int t) { return Ab + t * 32; };
  auto gb = [&](int t) { return Bb + t * 32; };
  gemm_core(ga, gb, 1024, 1024, 32, lds, tid, acc);
  const int l = tid & 63, w = tid >> 6;
  const int wm = w >> 2, wn = w & 3;
  const int lr = l & 15, lk = l >> 4;
  const int n0 = (nt & 3) * 256;
  // acc -> LDS f16 (rotated to avoid write-bank conflicts), then linear stores
#pragma unroll
  for (int ai = 0; ai < 8; ++ai) {
    const int rbase = wm * 128 + (ai >> 2) * 64 + (ai & 3) * 16 + lk * 4;
#pragma unroll
    for (int j = 0; j < 4; ++j) {
      const int col = wn * 64 + j * 16 + lr;
      const float bvv = bsel[n0 + col];
#pragma unroll
      for (int r = 0; r < 4; ++r) {
        const int row = rbase + r;
        const float v = acc[ai][j][r] + bvv;
        if (sel < 2)  // [row][col] rotated
          lds[row * 256 + ((col + (row >> 2) * 16) & 255)] = (_Float16)v;
        else          // transposed: [d=col][t=row] rotated
          lds[col * 256 + ((row + (col >> 2) * 16) & 255)] = (_Float16)v;
      }
    }
  }
  __syncthreads();
#pragma unroll
  for (int i = 0; i < 16; ++i) {
    const int c = i * 512 + tid;
    const int row = c >> 5, c8 = c & 31;
    half8 v = *(const half8*)&lds[row * 256 + ((c8 * 8 + (row >> 2) * 16) & 255)];
    if (sel < 2) {
      _Float16* Out = sel == 0 ? Qh : Kh;
      *(half8*)&Out[(size_t)(mt * 256 + row) * 1024 + n0 + c8 * 8] = v;
    } else {
      const int bb = mt >> 3, t0 = (mt & 7) * 256;
      *(half8*)&VT[((size_t)bb * 1024 + n0 + row) * 2048 + t0 + c8 * 8] = v;
    }
  }
}

// Causal QK^T: blockIdx.x = tri tile (qt,jt<=qt) of 256^2 -> compact f32 S
// [b][tri36][256][256], scaled, -inf above diagonal.
__global__ __launch_bounds__(512, 2) void gemm_qk(const _Float16* __restrict__ Qh,
                                                  const _Float16* __restrict__ Kh,
                                                  float* __restrict__ Sc) {
  __shared__ _Float16 lds[65536];
  const int tid = threadIdx.x;
  const int idx = blockIdx.x, bb = blockIdx.y;
  int qt = 0;
  while ((qt + 1) * (qt + 2) / 2 <= idx) ++qt;
  const int jt = idx - qt * (qt + 1) / 2;
  const _Float16* Ab = Qh + ((size_t)bb * 2048 + qt * 256) * 1024;
  const _Float16* Bb = Kh + ((size_t)bb * 2048 + jt * 256) * 1024;
  f32x4 acc[8][4] = {};
  auto ga = [&](int t) { return Ab + t * 32; };
  auto gb = [&](int t) { return Bb + t * 32; };
  gemm_core(ga, gb, 1024, 1024, 32, lds, tid, acc);
  const int l = tid & 63, w = tid >> 6;
  const int wm = w >> 2, wn = w & 3;
  const int lr = l & 15, lk = l >> 4;
  float* St = Sc + ((size_t)bb * 36 + idx) * 65536;
  const float NINF = -__builtin_inff();
#pragma unroll
  for (int ai = 0; ai < 8; ++ai) {
    const int rbase = wm * 128 + (ai >> 2) * 64 + (ai & 3) * 16 + lk * 4;
#pragma unroll
    for (int j = 0; j < 4; ++j) {
      const int ck = wn * 64 + j * 16 + lr;
      const int kg = jt * 256 + ck;
#pragma unroll
      for (int r = 0; r < 4; ++r) {
        const int rq = rbase + r;
        const int qg = qt * 256 + rq;
        St[(size_t)rq * 256 + ck] = (kg <= qg) ? acc[ai][j][r] * ATT_SCALE : NINF;
      }
    }
  }
}

// One wave per row: in-register softmax over compact S row, writes f16 P.
__global__ __launch_bounds__(256) void softmax_p(const float* __restrict__ Sc,
                                                 _Float16* __restrict__ Pc) {
  const int l = threadIdx.x & 63;
  const int gid = blockIdx.x * 4 + (threadIdx.x >> 6);
  const int b = gid >> 11, q = gid & 2047;
  const int qt = q >> 8, rq = q & 255;
  const int ntile = qt + 1;
  const size_t base = ((size_t)b * 36 + (size_t)(qt * (qt + 1) / 2)) * 65536 +
                      (size_t)rq * 256 + l * 4;
  float vx[32];
  float m = -__builtin_inff();
#pragma unroll
  for (int c = 0; c < 8; ++c) {
    float4 t = {-__builtin_inff(), -__builtin_inff(), -__builtin_inff(), -__builtin_inff()};
    if (c < ntile) t = *(const float4*)&Sc[base + (size_t)c * 65536];
    vx[4 * c] = t.x; vx[4 * c + 1] = t.y; vx[4 * c + 2] = t.z; vx[4 * c + 3] = t.w;
    m = fmaxf(m, fmaxf(fmaxf(t.x, t.y), fmaxf(t.z, t.w)));
  }
#pragma unroll
  for (int s = 1; s < 64; s <<= 1) m = fmaxf(m, __shfl_xor(m, s, 64));
  float sum = 0.f;
#pragma unroll
  for (int i = 0; i < 32; ++i) { vx[i] = __expf(vx[i] - m); sum += vx[i]; }
#pragma unroll
  for (int s = 1; s < 64; s <<= 1) sum += __shfl_xor(sum, s, 64);
  const float inv = 1.f / sum;
  _Float16* Pb = Pc + base;
#pragma unroll
  for (int c = 0; c < 8; ++c) {
    if (c < ntile) {
      half8* dst = (half8*)&Pb[(size_t)c * 65536];
      _Float16 p0 = (_Float16)(vx[4 * c] * inv);
      _Float16 p1 = (_Float16)(vx[4 * c + 1] * inv);
      _Float16 p2 = (_Float16)(vx[4 * c + 2] * inv);
      _Float16 p3 = (_Float16)(vx[4 * c + 3] * inv);
      _Float16 tmp[4] = {p0, p1, p2, p3};
      *(uint64_t*)&Pb[(size_t)c * 65536] = *(const uint64_t*)tmp;
      (void)dst;
    }
  }
}

// O[b,q,d] = sum_k P[b,q,k]*VT[b,d,k], causal k range per q-tile.
__global__ __launch_bounds__(512, 2) void gemm_pv(const _Float16* __restrict__ Pc,
                                                  const _Float16* __restrict__ VT,
                                                  float* __restrict__ O) {
  __shared__ _Float16 lds[65536];
  const int tid = threadIdx.x;
  const int dt = blockIdx.x, qt = 7 - blockIdx.y, b = blockIdx.z;
  const _Float16* Pb = Pc + ((size_t)b * 36 + (size_t)(qt * (qt + 1) / 2)) * 65536;
  const _Float16* Vb = VT + ((size_t)b * 1024 + dt * 256) * 2048;
  f32x4 acc[8][4] = {};
  auto ga = [&](int t) { return Pb + (size_t)(t >> 3) * 65536 + (t & 7) * 32; };
  auto gb = [&](int t) { return Vb + t * 32; };
  gemm_core(ga, gb, 256, 2048, (qt + 1) * 8, lds, tid, acc);
  const int l = tid & 63, w = tid >> 6;
  const int wm = w >> 2, wn = w & 3;
  const int lr = l & 15, lk = l >> 4;
#pragma unroll
  for (int ai = 0; ai < 8; ++ai) {
    const int rbase = qt * 256 + wm * 128 + (ai >> 2) * 64 + (ai & 3) * 16 + lk * 4;
#pragma unroll
    for (int j = 0; j < 4; ++j) {
      const int cg = dt * 256 + wn * 64 + j * 16 + lr;
#pragma unroll
      for (int r = 0; r < 4; ++r)
        O[((size_t)b * 2048 + rbase + r) * 1024 + cg] = acc[ai][j][r];
    }
  }
}

extern "C" void kernel_launch(void* const* d_in, const int* in_sizes, int n_in,
                              void* d_out, int out_size, void* d_ws, size_t ws_size,
                              hipStream_t stream) {
  const float* x    = (const float*)d_in[0];
  const float* Wq_w = (const float*)d_in[1];
  const float* Wq_b = (const float*)d_in[2];
  const float* Wk_w = (const float*)d_in[3];
  const float* Wk_b = (const float*)d_in[4];
  const float* Wv_w = (const float*)d_in[5];
  const float* Wv_b = (const float*)d_in[6];
  float* out = (float*)d_out;
  char* ws = (char*)d_ws;
  // Workspace (peak ~176 MB):
  _Float16* xh  = (_Float16*)(ws);              // 32 MiB (dead after proj)
  _Float16* Wqh = (_Float16*)(ws + 33554432);   // 2 MiB
  _Float16* Wkh = (_Float16*)(ws + 35651584);   // 2 MiB
  _Float16* Wvh = (_Float16*)(ws + 37748736);   // 2 MiB
  float*    Sc  = (float*)(ws);                 // compact tri S f32 (aliases xh+W)
  _Float16* Qh  = (_Float16*)(ws + 75497472);   // 32 MiB
  _Float16* Kh  = (_Float16*)(ws + 109051904);  // 32 MiB
  _Float16* Pc  = (_Float16*)(ws + 75497472);   // compact tri P f16 (aliases Q/K)
  _Float16* VT  = (_Float16*)(ws + 142606336);  // 32 MiB

  cvt_f32_f16<<<8192, 256, 0, stream>>>(x, xh, 2097152);
  cvt_f32_f16<<<512, 256, 0, stream>>>(Wq_w, Wqh, 131072);
  cvt_f32_f16<<<512, 256, 0, stream>>>(Wk_w, Wkh, 131072);
  cvt_f32_f16<<<512, 256, 0, stream>>>(Wv_w, Wvh, 131072);
  gemm_qkv<<<768, 512, 0, stream>>>(xh, Wqh, Wkh, Wvh, Wq_b, Wk_b, Wv_b, Qh, Kh, VT);
  gemm_qk<<<dim3(36, 8), 512, 0, stream>>>(Qh, Kh, Sc);
  softmax_p<<<4096, 256, 0, stream>>>(Sc, Pc);
  gemm_pv<<<dim3(4, 8, 8), 512, 0, stream>>>(Pc, VT, out);
}

// Round 5
// 313.037 us; speedup vs baseline: 1.0257x; 1.0257x over previous
//
#include <hip/hip_runtime.h>

// ScaledAttention B=8,T=2048,D=1024 single-head, SCALE=1/8.
// cvt f32->f16 -> fused QKV proj -> causal QK^T (compact f32 S) -> row softmax
// -> PV. GEMM core = m201-style: 256x256 tile, BK=64, 8 waves (2Mx4N),
// [128][64] half-tiles with st_16x32 XOR swizzle (pre-swizzled global source,
// swizzled ds_read), 4 phases/K-tile (one C-quadrant each, frags held),
// 1 half-tile staged per phase, counted vmcnt(4) once per K-tile.

typedef float f32x4 __attribute__((ext_vector_type(4)));
typedef _Float16 half8 __attribute__((ext_vector_type(8)));

#define DEVINL __device__ __forceinline__
static constexpr float ATT_SCALE = 0.125f;  // 1/sqrt(1024/16)

DEVINL void gload_lds16(const _Float16* g, _Float16* l) {
  __builtin_amdgcn_global_load_lds((const __attribute__((address_space(1))) void*)g,
                                   (__attribute__((address_space(3))) void*)l, 16, 0, 0);
}

#define PH_MID() __builtin_amdgcn_s_barrier(); \
    asm volatile("s_waitcnt lgkmcnt(0)" ::: "memory"); \
    __builtin_amdgcn_sched_barrier(0); __builtin_amdgcn_s_setprio(1);
#define PH_END() __builtin_amdgcn_s_setprio(0); __builtin_amdgcn_s_barrier();

// LDS map (bytes): buf b at b*65536: A0@0 A1@16384 B0@32768 B1@49152.
// Half-tile = [128 rows][64 cols] f16, element (r,c) at byte
// s = u ^ (((u>>9)&1)<<5), u = r*128 + c*2   (st_16x32 swizzle).
template <class GA, class GB>
DEVINL void gemm_core(GA ga, GB gb, int lda, int ldb, int NT,
                      char* ldsb, int tid, f32x4 acc[8][4]) {
  const int l = tid & 63, w = tid >> 6;
  const int wm = w >> 2, wn = w & 3;
  const int lr = l & 15, lk = l >> 4;
  // staging source map: dst chunk d -> element (srow, scol*8)
  int srow[2], scol[2];
#pragma unroll
  for (int i = 0; i < 2; ++i) {
    const int d = i * 8192 + w * 1024 + l * 16;
    const int u = d ^ (((d >> 9) & 1) << 5);
    srow[i] = u >> 7;
    scol[i] = (u >> 4) & 7;
  }
  // fragment read bases (swizzled byte offsets)
  const int xo = (lr & 4) << 3;  // ((row>>2)&1)<<5
  const int abase = lr * 128 + ((lk * 16) ^ xo);
  const int bbase = (wn & 1) * 8192 + lr * 128 + ((lk * 16) ^ xo);

  auto STG = [&](const _Float16* __restrict__ g0, int ld, int bufb, int slot) {
    char* dst = ldsb + bufb * 65536 + slot * 16384;
#pragma unroll
    for (int i = 0; i < 2; ++i)
      gload_lds16(g0 + (size_t)srow[i] * ld + scol[i] * 8,
                  (_Float16*)(dst + i * 8192 + w * 1024));
  };
  auto LDA8 = [&](int bufb, int ih, half8 a[4][2]) {
    const char* sA = ldsb + bufb * 65536 + wm * 16384;
#pragma unroll
    for (int i = 0; i < 4; ++i)
#pragma unroll
      for (int kk = 0; kk < 2; ++kk)
        a[i][kk] = *(const half8*)(sA + (abase + ih * 8192 + i * 2048 + kk * 64));
  };
  auto LDB4 = [&](int bufb, int jh, half8 bfr[2][2]) {
    const char* sB = ldsb + bufb * 65536 + 32768 + (wn >> 1) * 16384;
#pragma unroll
    for (int jj = 0; jj < 2; ++jj)
#pragma unroll
      for (int kk = 0; kk < 2; ++kk)
        bfr[jj][kk] = *(const half8*)(sB + (bbase + jh * 4096 + jj * 2048 + kk * 64));
  };

  // prologue: tile0 (A0,A1,B0,B1) + tile1 (B0,B1); wait for tile0
  STG(ga(0, 0), lda, 0, 0); STG(ga(0, 1), lda, 0, 1);
  STG(gb(0, 0), ldb, 0, 2); STG(gb(0, 1), ldb, 0, 3);
  STG(gb(1, 0), ldb, 1, 2); STG(gb(1, 1), ldb, 1, 3);
  asm volatile("s_waitcnt vmcnt(4)" ::: "memory");
  __builtin_amdgcn_s_barrier();

  half8 a[4][2], bf0[2][2], bf1[2][2];
  for (int t = 0; t < NT; ++t) {
    const int bufb = t & 1, obuf = bufb ^ 1;
    // p1 (ih0,jh0): read A(ih0)+B(jh0); stage A0(t+1) -> other buf
    LDA8(bufb, 0, a);
    LDB4(bufb, 0, bf0);
    if (t + 1 < NT) STG(ga(t + 1, 0), lda, obuf, 0);
    PH_MID();
#pragma unroll
    for (int kk = 0; kk < 2; ++kk)
#pragma unroll
      for (int i = 0; i < 4; ++i)
#pragma unroll
        for (int jj = 0; jj < 2; ++jj)
          acc[i][jj] = __builtin_amdgcn_mfma_f32_16x16x32_f16(a[i][kk], bf0[jj][kk], acc[i][jj], 0, 0, 0);
    PH_END();
    // p2 (ih0,jh1): read B(jh1); stage A1(t+1)
    LDB4(bufb, 1, bf1);
    if (t + 1 < NT) STG(ga(t + 1, 1), lda, obuf, 1);
    PH_MID();
#pragma unroll
    for (int kk = 0; kk < 2; ++kk)
#pragma unroll
      for (int i = 0; i < 4; ++i)
#pragma unroll
        for (int jj = 0; jj < 2; ++jj)
          acc[i][2 + jj] = __builtin_amdgcn_mfma_f32_16x16x32_f16(a[i][kk], bf1[jj][kk], acc[i][2 + jj], 0, 0, 0);
    PH_END();
    // p3 (ih1,jh0): read A(ih1); stage B0(t+2) -> own buf
    LDA8(bufb, 1, a);
    if (t + 2 < NT) STG(gb(t + 2, 0), ldb, bufb, 2);
    PH_MID();
#pragma unroll
    for (int kk = 0; kk < 2; ++kk)
#pragma unroll
      for (int i = 0; i < 4; ++i)
#pragma unroll
        for (int jj = 0; jj < 2; ++jj)
          acc[4 + i][jj] = __builtin_amdgcn_mfma_f32_16x16x32_f16(a[i][kk], bf0[jj][kk], acc[4 + i][jj], 0, 0, 0);
    PH_END();
    // p4 (ih1,jh1): no reads; stage B1(t+2); counted wait
    if (t + 2 < NT) STG(gb(t + 2, 1), ldb, bufb, 3);
    PH_MID();
#pragma unroll
    for (int kk = 0; kk < 2; ++kk)
#pragma unroll
      for (int i = 0; i < 4; ++i)
#pragma unroll
        for (int jj = 0; jj < 2; ++jj)
          acc[4 + i][2 + jj] = __builtin_amdgcn_mfma_f32_16x16x32_f16(a[i][kk], bf1[jj][kk], acc[4 + i][2 + jj], 0, 0, 0);
    __builtin_amdgcn_s_setprio(0);
    if (t + 2 < NT)      { asm volatile("s_waitcnt vmcnt(4)" ::: "memory"); }
    else if (t + 1 < NT) { asm volatile("s_waitcnt vmcnt(0)" ::: "memory"); }
    __builtin_amdgcn_s_barrier();
  }
}

__global__ __launch_bounds__(256) void cvt_f32_f16(const float* __restrict__ in,
                                                   _Float16* __restrict__ out, int n8) {
  int i = blockIdx.x * 256 + threadIdx.x;
  if (i >= n8) return;
  const float4* p = (const float4*)in + (size_t)i * 2;
  float4 v0 = p[0], v1 = p[1];
  half8 h;
  h[0] = (_Float16)v0.x; h[1] = (_Float16)v0.y; h[2] = (_Float16)v0.z; h[3] = (_Float16)v0.w;
  h[4] = (_Float16)v1.x; h[5] = (_Float16)v1.y; h[6] = (_Float16)v1.z; h[7] = (_Float16)v1.w;
  *((half8*)out + i) = h;
}

// Fused QKV: C[m,n]=sum_k x[m,k]W[n,k]+b[n], M=16384, N=3072, K=1024.
__global__ __launch_bounds__(512, 2) void gemm_qkv(
    const _Float16* __restrict__ xh, const _Float16* __restrict__ Wqh,
    const _Float16* __restrict__ Wkh, const _Float16* __restrict__ Wvh,
    const float* __restrict__ bq, const float* __restrict__ bk,
    const float* __restrict__ bv, _Float16* __restrict__ Qh,
    _Float16* __restrict__ Kh, _Float16* __restrict__ VT) {
  __shared__ _Float16 lds[65536];
  const int tid = threadIdx.x;
  const int bid = blockIdx.x;
  const int swz = (bid & 7) * 96 + (bid >> 3);  // XCD swizzle, 768%8==0
  const int mt = swz / 12, nt = swz % 12;
  const int sel = nt >> 2;
  const _Float16* Wsel = sel == 0 ? Wqh : (sel == 1 ? Wkh : Wvh);
  const float* bsel = sel == 0 ? bq : (sel == 1 ? bk : bv);
  const _Float16* Ab = xh + (size_t)mt * 256 * 1024;
  const _Float16* Bb = Wsel + (size_t)(nt & 3) * 256 * 1024;
  f32x4 acc[8][4] = {};
  auto ga = [&](int t, int h) { return Ab + (size_t)h * 128 * 1024 + t * 64; };
  auto gb = [&](int t, int h) { return Bb + (size_t)h * 128 * 1024 + t * 64; };
  gemm_core(ga, gb, 1024, 1024, 16, (char*)lds, tid, acc);
  const int l = tid & 63, w = tid >> 6;
  const int wm = w >> 2, wn = w & 3;
  const int lr = l & 15, lk = l >> 4;
  const int n0 = (nt & 3) * 256;
  __syncthreads();
  // acc -> LDS f16 (rotated layout), then coalesced 16B stores
#pragma unroll
  for (int ai = 0; ai < 8; ++ai) {
    const int rbase = wm * 128 + (ai >> 2) * 64 + (ai & 3) * 16 + lk * 4;
#pragma unroll
    for (int j = 0; j < 4; ++j) {
      const int col = wn * 64 + j * 16 + lr;
      const float bvv = bsel[n0 + col];
#pragma unroll
      for (int r = 0; r < 4; ++r) {
        const int row = rbase + r;
        const float v = acc[ai][j][r] + bvv;
        if (sel < 2)
          lds[row * 256 + ((col + (row >> 2) * 16) & 255)] = (_Float16)v;
        else
          lds[col * 256 + ((row + (col >> 2) * 16) & 255)] = (_Float16)v;
      }
    }
  }
  __syncthreads();
#pragma unroll
  for (int i = 0; i < 16; ++i) {
    const int c = i * 512 + tid;
    const int row = c >> 5, c8 = c & 31;
    half8 v = *(const half8*)&lds[row * 256 + ((c8 * 8 + (row >> 2) * 16) & 255)];
    if (sel < 2) {
      _Float16* Out = sel == 0 ? Qh : Kh;
      *(half8*)&Out[(size_t)(mt * 256 + row) * 1024 + n0 + c8 * 8] = v;
    } else {
      const int bb = mt >> 3, t0 = (mt & 7) * 256;
      *(half8*)&VT[((size_t)bb * 1024 + n0 + row) * 2048 + t0 + c8 * 8] = v;
    }
  }
}

// Causal QK^T: blockIdx.x = tri tile (qt,jt<=qt) of 256^2 -> compact f32 S
// [b][tri36][256][256], scaled, -inf above diagonal.
__global__ __launch_bounds__(512, 2) void gemm_qk(const _Float16* __restrict__ Qh,
                                                  const _Float16* __restrict__ Kh,
                                                  float* __restrict__ Sc) {
  __shared__ _Float16 lds[65536];
  const int tid = threadIdx.x;
  const int idx = blockIdx.x, bb = blockIdx.y;
  int qt = 0;
  while ((qt + 1) * (qt + 2) / 2 <= idx) ++qt;
  const int jt = idx - qt * (qt + 1) / 2;
  const _Float16* Ab = Qh + ((size_t)bb * 2048 + qt * 256) * 1024;
  const _Float16* Bb = Kh + ((size_t)bb * 2048 + jt * 256) * 1024;
  f32x4 acc[8][4] = {};
  auto ga = [&](int t, int h) { return Ab + (size_t)h * 128 * 1024 + t * 64; };
  auto gb = [&](int t, int h) { return Bb + (size_t)h * 128 * 1024 + t * 64; };
  gemm_core(ga, gb, 1024, 1024, 16, (char*)lds, tid, acc);
  const int l = tid & 63, w = tid >> 6;
  const int wm = w >> 2, wn = w & 3;
  const int lr = l & 15, lk = l >> 4;
  float* St = Sc + ((size_t)bb * 36 + idx) * 65536;
  const float NINF = -__builtin_inff();
#pragma unroll
  for (int ai = 0; ai < 8; ++ai) {
    const int rbase = wm * 128 + (ai >> 2) * 64 + (ai & 3) * 16 + lk * 4;
#pragma unroll
    for (int j = 0; j < 4; ++j) {
      const int ck = wn * 64 + j * 16 + lr;
      const int kg = jt * 256 + ck;
#pragma unroll
      for (int r = 0; r < 4; ++r) {
        const int rq = rbase + r;
        const int qg = qt * 256 + rq;
        St[(size_t)rq * 256 + ck] = (kg <= qg) ? acc[ai][j][r] * ATT_SCALE : NINF;
      }
    }
  }
}

// One wave per row: in-register softmax over compact S row, writes f16 P.
__global__ __launch_bounds__(256) void softmax_p(const float* __restrict__ Sc,
                                                 _Float16* __restrict__ Pc) {
  const int l = threadIdx.x & 63;
  const int gid = blockIdx.x * 4 + (threadIdx.x >> 6);
  const int b = gid >> 11, q = gid & 2047;
  const int qt = q >> 8, rq = q & 255;
  const int ntile = qt + 1;
  const size_t base = ((size_t)b * 36 + (size_t)(qt * (qt + 1) / 2)) * 65536 +
                      (size_t)rq * 256 + l * 4;
  float vx[32];
  float m = -__builtin_inff();
#pragma unroll
  for (int c = 0; c < 8; ++c) {
    float4 t = {-__builtin_inff(), -__builtin_inff(), -__builtin_inff(), -__builtin_inff()};
    if (c < ntile) t = *(const float4*)&Sc[base + (size_t)c * 65536];
    vx[4 * c] = t.x; vx[4 * c + 1] = t.y; vx[4 * c + 2] = t.z; vx[4 * c + 3] = t.w;
    m = fmaxf(m, fmaxf(fmaxf(t.x, t.y), fmaxf(t.z, t.w)));
  }
#pragma unroll
  for (int s = 1; s < 64; s <<= 1) m = fmaxf(m, __shfl_xor(m, s, 64));
  float sum = 0.f;
#pragma unroll
  for (int i = 0; i < 32; ++i) { vx[i] = __expf(vx[i] - m); sum += vx[i]; }
#pragma unroll
  for (int s = 1; s < 64; s <<= 1) sum += __shfl_xor(sum, s, 64);
  const float inv = 1.f / sum;
  _Float16* Pb = Pc + base;
#pragma unroll
  for (int c = 0; c < 8; ++c) {
    if (c < ntile) {
      _Float16 tmp[4];
      tmp[0] = (_Float16)(vx[4 * c] * inv);
      tmp[1] = (_Float16)(vx[4 * c + 1] * inv);
      tmp[2] = (_Float16)(vx[4 * c + 2] * inv);
      tmp[3] = (_Float16)(vx[4 * c + 3] * inv);
      *(uint64_t*)&Pb[(size_t)c * 65536] = *(const uint64_t*)tmp;
    }
  }
}

// O[b,q,d] = sum_k P[b,q,k]*VT[b,d,k], causal k range per q-tile.
__global__ __launch_bounds__(512, 2) void gemm_pv(const _Float16* __restrict__ Pc,
                                                  const _Float16* __restrict__ VT,
                                                  float* __restrict__ O) {
  __shared__ _Float16 lds[65536];
  const int tid = threadIdx.x;
  const int dt = blockIdx.x, qt = 7 - blockIdx.y, b = blockIdx.z;
  const _Float16* Pb = Pc + ((size_t)b * 36 + (size_t)(qt * (qt + 1) / 2)) * 65536;
  const _Float16* Vb = VT + ((size_t)b * 1024 + dt * 256) * 2048;
  f32x4 acc[8][4] = {};
  auto ga = [&](int t, int h) {
    return Pb + (size_t)(t >> 2) * 65536 + (size_t)h * 128 * 256 + (t & 3) * 64;
  };
  auto gb = [&](int t, int h) { return Vb + (size_t)h * 128 * 2048 + t * 64; };
  gemm_core(ga, gb, 256, 2048, (qt + 1) * 4, (char*)lds, tid, acc);
  const int l = tid & 63, w = tid >> 6;
  const int wm = w >> 2, wn = w & 3;
  const int lr = l & 15, lk = l >> 4;
#pragma unroll
  for (int ai = 0; ai < 8; ++ai) {
    const int rbase = qt * 256 + wm * 128 + (ai >> 2) * 64 + (ai & 3) * 16 + lk * 4;
#pragma unroll
    for (int j = 0; j < 4; ++j) {
      const int cg = dt * 256 + wn * 64 + j * 16 + lr;
#pragma unroll
      for (int r = 0; r < 4; ++r)
        O[((size_t)b * 2048 + rbase + r) * 1024 + cg] = acc[ai][j][r];
    }
  }
}

extern "C" void kernel_launch(void* const* d_in, const int* in_sizes, int n_in,
                              void* d_out, int out_size, void* d_ws, size_t ws_size,
                              hipStream_t stream) {
  const float* x    = (const float*)d_in[0];
  const float* Wq_w = (const float*)d_in[1];
  const float* Wq_b = (const float*)d_in[2];
  const float* Wk_w = (const float*)d_in[3];
  const float* Wk_b = (const float*)d_in[4];
  const float* Wv_w = (const float*)d_in[5];
  const float* Wv_b = (const float*)d_in[6];
  float* out = (float*)d_out;
  char* ws = (char*)d_ws;
  _Float16* xh  = (_Float16*)(ws);              // 32 MiB (dead after proj)
  _Float16* Wqh = (_Float16*)(ws + 33554432);   // 2 MiB
  _Float16* Wkh = (_Float16*)(ws + 35651584);   // 2 MiB
  _Float16* Wvh = (_Float16*)(ws + 37748736);   // 2 MiB
  float*    Sc  = (float*)(ws);                 // compact tri S f32 (aliases xh+W)
  _Float16* Qh  = (_Float16*)(ws + 75497472);   // 32 MiB
  _Float16* Kh  = (_Float16*)(ws + 109051904);  // 32 MiB
  _Float16* Pc  = (_Float16*)(ws + 75497472);   // compact tri P f16 (aliases Q/K)
  _Float16* VT  = (_Float16*)(ws + 142606336);  // 32 MiB

  cvt_f32_f16<<<8192, 256, 0, stream>>>(x, xh, 2097152);
  cvt_f32_f16<<<512, 256, 0, stream>>>(Wq_w, Wqh, 131072);
  cvt_f32_f16<<<512, 256, 0, stream>>>(Wk_w, Wkh, 131072);
  cvt_f32_f16<<<512, 256, 0, stream>>>(Wv_w, Wvh, 131072);
  gemm_qkv<<<768, 512, 0, stream>>>(xh, Wqh, Wkh, Wvh, Wq_b, Wk_b, Wv_b, Qh, Kh, VT);
  gemm_qk<<<dim3(36, 8), 512, 0, stream>>>(Qh, Kh, Sc);
  softmax_p<<<4096, 256, 0, stream>>>(Sc, Pc);
  gemm_pv<<<dim3(4, 8, 8), 512, 0, stream>>>(Pc, VT, out);
}

// Round 6
// 299.252 us; speedup vs baseline: 1.0730x; 1.0461x over previous
//
#include <hip/hip_runtime.h>

// ScaledAttention B=8,T=2048,D=1024 single-head, SCALE=1/8.
// cvt f32->f16 -> fused QKV proj -> causal QK^T (compact f32 S) -> row softmax
// -> PV. GEMM core: 256x256 tile, BK=64, 8 waves (2Mx4N), [128][64] f16
// half-tiles. LDS swizzle: 16B-chunk index XOR (row&7)  (byte ^= (row&7)<<4),
// applied on BOTH the pre-swizzled global staging source and the ds_read side
// -> 2-way (free) bank access for all fragment reads. 4 phases/K-tile,
// frags held across phases, counted vmcnt(4) once per K-tile.

typedef float f32x4 __attribute__((ext_vector_type(4)));
typedef _Float16 half8 __attribute__((ext_vector_type(8)));

#define DEVINL __device__ __forceinline__
static constexpr float ATT_SCALE = 0.125f;  // 1/sqrt(1024/16)

DEVINL void gload_lds16(const _Float16* g, _Float16* l) {
  __builtin_amdgcn_global_load_lds((const __attribute__((address_space(1))) void*)g,
                                   (__attribute__((address_space(3))) void*)l, 16, 0, 0);
}

#define PH_MID() __builtin_amdgcn_s_barrier(); \
    asm volatile("s_waitcnt lgkmcnt(0)" ::: "memory"); \
    __builtin_amdgcn_sched_barrier(0); __builtin_amdgcn_s_setprio(1);
#define PH_END() __builtin_amdgcn_s_setprio(0); __builtin_amdgcn_s_barrier();

// LDS map (bytes): buf b at b*65536: A0@0 A1@16384 B0@32768 B1@49152.
// Half-tile = [128 rows][64 cols] f16 (128B rows = 8 x 16B chunks).
// Element (r, chunk c) stored at physical chunk c ^ (r&7) of row r.
template <class GA, class GB>
DEVINL void gemm_core(GA ga, GB gb, int lda, int ldb, int NT,
                      char* ldsb, int tid, f32x4 acc[8][4]) {
  const int l = tid & 63, w = tid >> 6;
  const int wm = w >> 2, wn = w & 3;
  const int lr = l & 15, lk = l >> 4;
  // staging source map: dst 16B-chunk P = i*512 + w*64 + l -> (row, logical chunk)
  int srow[2], scol[2];
#pragma unroll
  for (int i = 0; i < 2; ++i) {
    const int P = i * 512 + w * 64 + l;
    srow[i] = P >> 3;
    scol[i] = (P & 7) ^ (srow[i] & 7);  // logical chunk = col/8
  }
  // fragment read: row-local base + swizzled chunk for kk=0/1 (chunk bit2 = kk)
  const int ch0 = ((lk ^ (lr & 7)) << 4);
  const int ch1 = (((lk | 4) ^ (lr & 7)) << 4);
  const int abase = lr * 128;
  const int bbase = (wn & 1) * 8192 + lr * 128;

  auto STG = [&](const _Float16* __restrict__ g0, int ld, int bufb, int slot) {
    char* dst = ldsb + bufb * 65536 + slot * 16384;
#pragma unroll
    for (int i = 0; i < 2; ++i)
      gload_lds16(g0 + (size_t)srow[i] * ld + scol[i] * 8,
                  (_Float16*)(dst + i * 8192 + w * 1024));
  };
  auto LDA8 = [&](int bufb, int ih, half8 a[4][2]) {
    const char* sA = ldsb + bufb * 65536 + wm * 16384 + ih * 8192;
#pragma unroll
    for (int i = 0; i < 4; ++i) {
      a[i][0] = *(const half8*)(sA + abase + i * 2048 + ch0);
      a[i][1] = *(const half8*)(sA + abase + i * 2048 + ch1);
    }
  };
  auto LDB4 = [&](int bufb, int jh, half8 bfr[2][2]) {
    const char* sB = ldsb + bufb * 65536 + 32768 + (wn >> 1) * 16384 + jh * 4096;
#pragma unroll
    for (int jj = 0; jj < 2; ++jj) {
      bfr[jj][0] = *(const half8*)(sB + bbase + jj * 2048 + ch0);
      bfr[jj][1] = *(const half8*)(sB + bbase + jj * 2048 + ch1);
    }
  };

  // prologue: tile0 (A0,A1,B0,B1) + tile1 (B0,B1); wait for tile0
  STG(ga(0, 0), lda, 0, 0); STG(ga(0, 1), lda, 0, 1);
  STG(gb(0, 0), ldb, 0, 2); STG(gb(0, 1), ldb, 0, 3);
  STG(gb(1, 0), ldb, 1, 2); STG(gb(1, 1), ldb, 1, 3);
  asm volatile("s_waitcnt vmcnt(4)" ::: "memory");
  __builtin_amdgcn_s_barrier();

  half8 a[4][2], bf0[2][2], bf1[2][2];
  for (int t = 0; t < NT; ++t) {
    const int bufb = t & 1, obuf = bufb ^ 1;
    // p1 (ih0,jh0): read A(ih0)+B(jh0); stage A0(t+1) -> other buf
    LDA8(bufb, 0, a);
    LDB4(bufb, 0, bf0);
    if (t + 1 < NT) STG(ga(t + 1, 0), lda, obuf, 0);
    PH_MID();
#pragma unroll
    for (int kk = 0; kk < 2; ++kk)
#pragma unroll
      for (int i = 0; i < 4; ++i)
#pragma unroll
        for (int jj = 0; jj < 2; ++jj)
          acc[i][jj] = __builtin_amdgcn_mfma_f32_16x16x32_f16(a[i][kk], bf0[jj][kk], acc[i][jj], 0, 0, 0);
    PH_END();
    // p2 (ih0,jh1): read B(jh1); stage A1(t+1)
    LDB4(bufb, 1, bf1);
    if (t + 1 < NT) STG(ga(t + 1, 1), lda, obuf, 1);
    PH_MID();
#pragma unroll
    for (int kk = 0; kk < 2; ++kk)
#pragma unroll
      for (int i = 0; i < 4; ++i)
#pragma unroll
        for (int jj = 0; jj < 2; ++jj)
          acc[i][2 + jj] = __builtin_amdgcn_mfma_f32_16x16x32_f16(a[i][kk], bf1[jj][kk], acc[i][2 + jj], 0, 0, 0);
    PH_END();
    // p3 (ih1,jh0): read A(ih1); stage B0(t+2) -> own buf
    LDA8(bufb, 1, a);
    if (t + 2 < NT) STG(gb(t + 2, 0), ldb, bufb, 2);
    PH_MID();
#pragma unroll
    for (int kk = 0; kk < 2; ++kk)
#pragma unroll
      for (int i = 0; i < 4; ++i)
#pragma unroll
        for (int jj = 0; jj < 2; ++jj)
          acc[4 + i][jj] = __builtin_amdgcn_mfma_f32_16x16x32_f16(a[i][kk], bf0[jj][kk], acc[4 + i][jj], 0, 0, 0);
    PH_END();
    // p4 (ih1,jh1): no reads; stage B1(t+2); counted wait
    if (t + 2 < NT) STG(gb(t + 2, 1), ldb, bufb, 3);
    PH_MID();
#pragma unroll
    for (int kk = 0; kk < 2; ++kk)
#pragma unroll
      for (int i = 0; i < 4; ++i)
#pragma unroll
        for (int jj = 0; jj < 2; ++jj)
          acc[4 + i][2 + jj] = __builtin_amdgcn_mfma_f32_16x16x32_f16(a[i][kk], bf1[jj][kk], acc[4 + i][2 + jj], 0, 0, 0);
    __builtin_amdgcn_s_setprio(0);
    if (t + 2 < NT)      { asm volatile("s_waitcnt vmcnt(4)" ::: "memory"); }
    else if (t + 1 < NT) { asm volatile("s_waitcnt vmcnt(0)" ::: "memory"); }
    __builtin_amdgcn_s_barrier();
  }
}

__global__ __launch_bounds__(256) void cvt_f32_f16(const float* __restrict__ in,
                                                   _Float16* __restrict__ out, int n8) {
  int i = blockIdx.x * 256 + threadIdx.x;
  if (i >= n8) return;
  const float4* p = (const float4*)in + (size_t)i * 2;
  float4 v0 = p[0], v1 = p[1];
  half8 h;
  h[0] = (_Float16)v0.x; h[1] = (_Float16)v0.y; h[2] = (_Float16)v0.z; h[3] = (_Float16)v0.w;
  h[4] = (_Float16)v1.x; h[5] = (_Float16)v1.y; h[6] = (_Float16)v1.z; h[7] = (_Float16)v1.w;
  *((half8*)out + i) = h;
}

// Fused QKV: C[m,n]=sum_k x[m,k]W[n,k]+b[n], M=16384, N=3072, K=1024.
__global__ __launch_bounds__(512, 2) void gemm_qkv(
    const _Float16* __restrict__ xh, const _Float16* __restrict__ Wqh,
    const _Float16* __restrict__ Wkh, const _Float16* __restrict__ Wvh,
    const float* __restrict__ bq, const float* __restrict__ bk,
    const float* __restrict__ bv, _Float16* __restrict__ Qh,
    _Float16* __restrict__ Kh, _Float16* __restrict__ VT) {
  __shared__ _Float16 lds[65536];
  const int tid = threadIdx.x;
  const int bid = blockIdx.x;
  const int swz = (bid & 7) * 96 + (bid >> 3);  // XCD swizzle, 768%8==0
  const int mt = swz / 12, nt = swz % 12;
  const int sel = nt >> 2;
  const _Float16* Wsel = sel == 0 ? Wqh : (sel == 1 ? Wkh : Wvh);
  const float* bsel = sel == 0 ? bq : (sel == 1 ? bk : bv);
  const _Float16* Ab = xh + (size_t)mt * 256 * 1024;
  const _Float16* Bb = Wsel + (size_t)(nt & 3) * 256 * 1024;
  f32x4 acc[8][4] = {};
  auto ga = [&](int t, int h) { return Ab + (size_t)h * 128 * 1024 + t * 64; };
  auto gb = [&](int t, int h) { return Bb + (size_t)h * 128 * 1024 + t * 64; };
  gemm_core(ga, gb, 1024, 1024, 16, (char*)lds, tid, acc);
  const int l = tid & 63, w = tid >> 6;
  const int wm = w >> 2, wn = w & 3;
  const int lr = l & 15, lk = l >> 4;
  const int n0 = (nt & 3) * 256;
  __syncthreads();
  // acc -> LDS f16 (rotated layout), then coalesced 16B stores
#pragma unroll
  for (int ai = 0; ai < 8; ++ai) {
    const int rbase = wm * 128 + (ai >> 2) * 64 + (ai & 3) * 16 + lk * 4;
#pragma unroll
    for (int j = 0; j < 4; ++j) {
      const int col = wn * 64 + j * 16 + lr;
      const float bvv = bsel[n0 + col];
#pragma unroll
      for (int r = 0; r < 4; ++r) {
        const int row = rbase + r;
        const float v = acc[ai][j][r] + bvv;
        if (sel < 2)
          lds[row * 256 + ((col + (row >> 2) * 16) & 255)] = (_Float16)v;
        else
          lds[col * 256 + ((row + (col >> 2) * 16) & 255)] = (_Float16)v;
      }
    }
  }
  __syncthreads();
#pragma unroll
  for (int i = 0; i < 16; ++i) {
    const int c = i * 512 + tid;
    const int row = c >> 5, c8 = c & 31;
    half8 v = *(const half8*)&lds[row * 256 + ((c8 * 8 + (row >> 2) * 16) & 255)];
    if (sel < 2) {
      _Float16* Out = sel == 0 ? Qh : Kh;
      *(half8*)&Out[(size_t)(mt * 256 + row) * 1024 + n0 + c8 * 8] = v;
    } else {
      const int bb = mt >> 3, t0 = (mt & 7) * 256;
      *(half8*)&VT[((size_t)bb * 1024 + n0 + row) * 2048 + t0 + c8 * 8] = v;
    }
  }
}

// Causal QK^T: blockIdx.x = tri tile (qt,jt<=qt) of 256^2 -> compact f32 S
// [b][tri36][256][256], scaled, -inf above diagonal.
__global__ __launch_bounds__(512, 2) void gemm_qk(const _Float16* __restrict__ Qh,
                                                  const _Float16* __restrict__ Kh,
                                                  float* __restrict__ Sc) {
  __shared__ _Float16 lds[65536];
  const int tid = threadIdx.x;
  const int idx = blockIdx.x, bb = blockIdx.y;
  int qt = 0;
  while ((qt + 1) * (qt + 2) / 2 <= idx) ++qt;
  const int jt = idx - qt * (qt + 1) / 2;
  const _Float16* Ab = Qh + ((size_t)bb * 2048 + qt * 256) * 1024;
  const _Float16* Bb = Kh + ((size_t)bb * 2048 + jt * 256) * 1024;
  f32x4 acc[8][4] = {};
  auto ga = [&](int t, int h) { return Ab + (size_t)h * 128 * 1024 + t * 64; };
  auto gb = [&](int t, int h) { return Bb + (size_t)h * 128 * 1024 + t * 64; };
  gemm_core(ga, gb, 1024, 1024, 16, (char*)lds, tid, acc);
  const int l = tid & 63, w = tid >> 6;
  const int wm = w >> 2, wn = w & 3;
  const int lr = l & 15, lk = l >> 4;
  float* St = Sc + ((size_t)bb * 36 + idx) * 65536;
  const float NINF = -__builtin_inff();
#pragma unroll
  for (int ai = 0; ai < 8; ++ai) {
    const int rbase = wm * 128 + (ai >> 2) * 64 + (ai & 3) * 16 + lk * 4;
#pragma unroll
    for (int j = 0; j < 4; ++j) {
      const int ck = wn * 64 + j * 16 + lr;
      const int kg = jt * 256 + ck;
#pragma unroll
      for (int r = 0; r < 4; ++r) {
        const int rq = rbase + r;
        const int qg = qt * 256 + rq;
        St[(size_t)rq * 256 + ck] = (kg <= qg) ? acc[ai][j][r] * ATT_SCALE : NINF;
      }
    }
  }
}

// One wave per row: in-register softmax over compact S row, writes f16 P.
__global__ __launch_bounds__(256) void softmax_p(const float* __restrict__ Sc,
                                                 _Float16* __restrict__ Pc) {
  const int l = threadIdx.x & 63;
  const int gid = blockIdx.x * 4 + (threadIdx.x >> 6);
  const int b = gid >> 11, q = gid & 2047;
  const int qt = q >> 8, rq = q & 255;
  const int ntile = qt + 1;
  const size_t base = ((size_t)b * 36 + (size_t)(qt * (qt + 1) / 2)) * 65536 +
                      (size_t)rq * 256 + l * 4;
  float vx[32];
  float m = -__builtin_inff();
#pragma unroll
  for (int c = 0; c < 8; ++c) {
    float4 t = {-__builtin_inff(), -__builtin_inff(), -__builtin_inff(), -__builtin_inff()};
    if (c < ntile) t = *(const float4*)&Sc[base + (size_t)c * 65536];
    vx[4 * c] = t.x; vx[4 * c + 1] = t.y; vx[4 * c + 2] = t.z; vx[4 * c + 3] = t.w;
    m = fmaxf(m, fmaxf(fmaxf(t.x, t.y), fmaxf(t.z, t.w)));
  }
#pragma unroll
  for (int s = 1; s < 64; s <<= 1) m = fmaxf(m, __shfl_xor(m, s, 64));
  float sum = 0.f;
#pragma unroll
  for (int i = 0; i < 32; ++i) { vx[i] = __expf(vx[i] - m); sum += vx[i]; }
#pragma unroll
  for (int s = 1; s < 64; s <<= 1) sum += __shfl_xor(sum, s, 64);
  const float inv = 1.f / sum;
  _Float16* Pb = Pc + base;
#pragma unroll
  for (int c = 0; c < 8; ++c) {
    if (c < ntile) {
      _Float16 tmp[4];
      tmp[0] = (_Float16)(vx[4 * c] * inv);
      tmp[1] = (_Float16)(vx[4 * c + 1] * inv);
      tmp[2] = (_Float16)(vx[4 * c + 2] * inv);
      tmp[3] = (_Float16)(vx[4 * c + 3] * inv);
      *(uint64_t*)&Pb[(size_t)c * 65536] = *(const uint64_t*)tmp;
    }
  }
}

// O[b,q,d] = sum_k P[b,q,k]*VT[b,d,k], causal k range per q-tile.
__global__ __launch_bounds__(512, 2) void gemm_pv(const _Float16* __restrict__ Pc,
                                                  const _Float16* __restrict__ VT,
                                                  float* __restrict__ O) {
  __shared__ _Float16 lds[65536];
  const int tid = threadIdx.x;
  const int dt = blockIdx.x, qt = 7 - blockIdx.y, b = blockIdx.z;
  const _Float16* Pb = Pc + ((size_t)b * 36 + (size_t)(qt * (qt + 1) / 2)) * 65536;
  const _Float16* Vb = VT + ((size_t)b * 1024 + dt * 256) * 2048;
  f32x4 acc[8][4] = {};
  auto ga = [&](int t, int h) {
    return Pb + (size_t)(t >> 2) * 65536 + (size_t)h * 128 * 256 + (t & 3) * 64;
  };
  auto gb = [&](int t, int h) { return Vb + (size_t)h * 128 * 2048 + t * 64; };
  gemm_core(ga, gb, 256, 2048, (qt + 1) * 4, (char*)lds, tid, acc);
  const int l = tid & 63, w = tid >> 6;
  const int wm = w >> 2, wn = w & 3;
  const int lr = l & 15, lk = l >> 4;
#pragma unroll
  for (int ai = 0; ai < 8; ++ai) {
    const int rbase = qt * 256 + wm * 128 + (ai >> 2) * 64 + (ai & 3) * 16 + lk * 4;
#pragma unroll
    for (int j = 0; j < 4; ++j) {
      const int cg = dt * 256 + wn * 64 + j * 16 + lr;
#pragma unroll
      for (int r = 0; r < 4; ++r)
        O[((size_t)b * 2048 + rbase + r) * 1024 + cg] = acc[ai][j][r];
    }
  }
}

extern "C" void kernel_launch(void* const* d_in, const int* in_sizes, int n_in,
                              void* d_out, int out_size, void* d_ws, size_t ws_size,
                              hipStream_t stream) {
  const float* x    = (const float*)d_in[0];
  const float* Wq_w = (const float*)d_in[1];
  const float* Wq_b = (const float*)d_in[2];
  const float* Wk_w = (const float*)d_in[3];
  const float* Wk_b = (const float*)d_in[4];
  const float* Wv_w = (const float*)d_in[5];
  const float* Wv_b = (const float*)d_in[6];
  float* out = (float*)d_out;
  char* ws = (char*)d_ws;
  _Float16* xh  = (_Float16*)(ws);              // 32 MiB (dead after proj)
  _Float16* Wqh = (_Float16*)(ws + 33554432);   // 2 MiB
  _Float16* Wkh = (_Float16*)(ws + 35651584);   // 2 MiB
  _Float16* Wvh = (_Float16*)(ws + 37748736);   // 2 MiB
  float*    Sc  = (float*)(ws);                 // compact tri S f32 (aliases xh+W)
  _Float16* Qh  = (_Float16*)(ws + 75497472);   // 32 MiB
  _Float16* Kh  = (_Float16*)(ws + 109051904);  // 32 MiB
  _Float16* Pc  = (_Float16*)(ws + 75497472);   // compact tri P f16 (aliases Q/K)
  _Float16* VT  = (_Float16*)(ws + 142606336);  // 32 MiB

  cvt_f32_f16<<<8192, 256, 0, stream>>>(x, xh, 2097152);
  cvt_f32_f16<<<512, 256, 0, stream>>>(Wq_w, Wqh, 131072);
  cvt_f32_f16<<<512, 256, 0, stream>>>(Wk_w, Wkh, 131072);
  cvt_f32_f16<<<512, 256, 0, stream>>>(Wv_w, Wvh, 131072);
  gemm_qkv<<<768, 512, 0, stream>>>(xh, Wqh, Wkh, Wvh, Wq_b, Wk_b, Wv_b, Qh, Kh, VT);
  gemm_qk<<<dim3(36, 8), 512, 0, stream>>>(Qh, Kh, Sc);
  softmax_p<<<4096, 256, 0, stream>>>(Sc, Pc);
  gemm_pv<<<dim3(4, 8, 8), 512, 0, stream>>>(Pc, VT, out);
}

// Round 7
// 294.717 us; speedup vs baseline: 1.0895x; 1.0154x over previous
//
#include <hip/hip_runtime.h>

// ScaledAttention B=8,T=2048,D=1024 single-head, SCALE=1/8.
// cvt f32->f16 -> fused QKV proj -> causal QK^T (compact f32 S) -> row softmax
// -> PV. GEMM core: 256x256 tile, BK=64, 8 waves (2Mx4N), [128][64] f16
// half-tiles, chunk-XOR (row&7) LDS swizzle (both sides). NEW in R7:
// cross-phase fragment prefetch (reads for phase p+1 issued during phase p,
// double-buffered reg sets, compiler-counted lgkm waits), counted vmcnt(2)
// at end-P2, compile-time LDs, peeled tail.

typedef float f32x4 __attribute__((ext_vector_type(4)));
typedef _Float16 half8 __attribute__((ext_vector_type(8)));

#define DEVINL __device__ __forceinline__
static constexpr float ATT_SCALE = 0.125f;  // 1/sqrt(1024/16)

DEVINL void gload_lds16(const _Float16* g, _Float16* l) {
  __builtin_amdgcn_global_load_lds((const __attribute__((address_space(1))) void*)g,
                                   (__attribute__((address_space(3))) void*)l, 16, 0, 0);
}

#define SBAR() __builtin_amdgcn_sched_barrier(0)
#define MM(AOFF, BOFF, ASET, BSET) \
  _Pragma("unroll") for (int kk_ = 0; kk_ < 2; ++kk_) \
  _Pragma("unroll") for (int i_ = 0; i_ < 4; ++i_) \
  _Pragma("unroll") for (int jj_ = 0; jj_ < 2; ++jj_) \
    acc[(AOFF) + i_][(BOFF) + jj_] = __builtin_amdgcn_mfma_f32_16x16x32_f16( \
        ASET[i_][kk_], BSET[jj_][kk_], acc[(AOFF) + i_][(BOFF) + jj_], 0, 0, 0);
#define PHASE_PRE() SBAR(); __builtin_amdgcn_s_barrier(); SBAR(); \
    __builtin_amdgcn_s_setprio(1)
#define PHASE_POST() __builtin_amdgcn_s_setprio(0); SBAR(); \
    __builtin_amdgcn_s_barrier(); SBAR()

// LDS map (bytes): buf b at b*65536: A-half0@0 A-half1@16384 B-half0@32768
// B-half1@49152. Half-tile = [128 rows][64 cols] f16; element (r, 16B-chunk c)
// stored at physical chunk c ^ (r&7).
template <int LDA, int LDB, class GA, class GB>
DEVINL void gemm_core(GA ga, GB gb, int NT, char* ldsb, int tid, f32x4 acc[8][4]) {
  const int l = tid & 63, w = tid >> 6;
  const int wm = w >> 2, wn = w & 3;
  const int lr = l & 15, lk = l >> 4;
  int srow[2], scol[2];
#pragma unroll
  for (int i = 0; i < 2; ++i) {
    const int P = i * 512 + w * 64 + l;
    srow[i] = P >> 3;
    scol[i] = (P & 7) ^ (srow[i] & 7);
  }
  const int ch0 = ((lk ^ (lr & 7)) << 4);
  const int ch1 = (((lk + 4) ^ (lr & 7)) << 4);
  const int abase = lr * 128;
  const int bbase = (wn & 1) * 8192 + lr * 128;

  half8 aA[4][2], aB[4][2], bA[2][2], bB[2][2];

  auto STGA = [&](int t, int h, int bufb) {
    const _Float16* g0 = ga(t, h);
    char* dst = ldsb + bufb * 65536 + h * 16384;
#pragma unroll
    for (int i = 0; i < 2; ++i)
      gload_lds16(g0 + (size_t)srow[i] * LDA + scol[i] * 8,
                  (_Float16*)(dst + i * 8192 + w * 1024));
  };
  auto STGB = [&](int t, int h, int bufb) {
    const _Float16* g0 = gb(t, h);
    char* dst = ldsb + bufb * 65536 + 32768 + h * 16384;
#pragma unroll
    for (int i = 0; i < 2; ++i)
      gload_lds16(g0 + (size_t)srow[i] * LDB + scol[i] * 8,
                  (_Float16*)(dst + i * 8192 + w * 1024));
  };
  auto RDA = [&](int bufb, int ih, half8 d[4][2]) {
    const char* sA = ldsb + bufb * 65536 + wm * 16384 + ih * 8192;
#pragma unroll
    for (int i = 0; i < 4; ++i) {
      d[i][0] = *(const half8*)(sA + abase + i * 2048 + ch0);
      d[i][1] = *(const half8*)(sA + abase + i * 2048 + ch1);
    }
  };
  auto RDB = [&](int bufb, int jh, half8 d[2][2]) {
    const char* sB = ldsb + bufb * 65536 + 32768 + (wn >> 1) * 16384 + jh * 4096;
#pragma unroll
    for (int jj = 0; jj < 2; ++jj) {
      d[jj][0] = *(const half8*)(sB + bbase + jj * 2048 + ch0);
      d[jj][1] = *(const half8*)(sB + bbase + jj * 2048 + ch1);
    }
  };

  // Per tile t: P0 uses (aA,bA), issues bB=B1(t), stages A0(t+1).
  //             P1 uses (aA,bB), issues aB=A1(t), stages A1(t+1).
  //             P2 uses (aB,bA), stages B0(t+2); vmcnt(2) -> buf t+1 resident.
  //             P3 uses (aB,bB), issues aA=A0(t+1)+bA=B0(t+1), stages B1(t+2).
  auto tile = [&](int t, bool stA, bool stB) {
    const int bufb = t & 1, obuf = bufb ^ 1;
    // P0
    RDB(bufb, 1, bB);
    if (stA) STGA(t + 1, 0, obuf);
    PHASE_PRE(); MM(0, 0, aA, bA); PHASE_POST();
    // P1
    RDA(bufb, 1, aB);
    if (stA) STGA(t + 1, 1, obuf);
    PHASE_PRE(); MM(0, 2, aA, bB); PHASE_POST();
    // P2
    if (stB) STGB(t + 2, 0, bufb);
    SBAR(); __builtin_amdgcn_s_barrier(); SBAR();
    __builtin_amdgcn_s_setprio(1);
    MM(4, 0, aB, bA);
    __builtin_amdgcn_s_setprio(0); SBAR();
    if (stB) { asm volatile("s_waitcnt vmcnt(2)" ::: "memory"); }
    else     { asm volatile("s_waitcnt vmcnt(0)" ::: "memory"); }
    __builtin_amdgcn_s_barrier(); SBAR();
    // P3
    if (stA) { RDA(obuf, 0, aA); RDB(obuf, 0, bA); }
    if (stB) STGB(t + 2, 1, bufb);
    PHASE_PRE(); MM(4, 2, aB, bB); PHASE_POST();
  };

  // prologue: tile0 (A0,A1,B0,B1) + tile1 (B0,B1); wait tile0; preload frags
  STGA(0, 0, 0); STGA(0, 1, 0); STGB(0, 0, 0); STGB(0, 1, 0);
  STGB(1, 0, 1); STGB(1, 1, 1);
  asm volatile("s_waitcnt vmcnt(4)" ::: "memory");
  __builtin_amdgcn_s_barrier(); SBAR();
  RDA(0, 0, aA); RDB(0, 0, bA);
  for (int t = 0; t < NT - 2; ++t) tile(t, true, true);
  tile(NT - 2, true, false);
  tile(NT - 1, false, false);
}

__global__ __launch_bounds__(256) void cvt_f32_f16(const float* __restrict__ in,
                                                   _Float16* __restrict__ out, int n8) {
  int i = blockIdx.x * 256 + threadIdx.x;
  if (i >= n8) return;
  const float4* p = (const float4*)in + (size_t)i * 2;
  float4 v0 = p[0], v1 = p[1];
  half8 h;
  h[0] = (_Float16)v0.x; h[1] = (_Float16)v0.y; h[2] = (_Float16)v0.z; h[3] = (_Float16)v0.w;
  h[4] = (_Float16)v1.x; h[5] = (_Float16)v1.y; h[6] = (_Float16)v1.z; h[7] = (_Float16)v1.w;
  *((half8*)out + i) = h;
}

// Fused QKV: C[m,n]=sum_k x[m,k]W[n,k]+b[n], M=16384, N=3072, K=1024.
__global__ __launch_bounds__(512, 2) void gemm_qkv(
    const _Float16* __restrict__ xh, const _Float16* __restrict__ Wqh,
    const _Float16* __restrict__ Wkh, const _Float16* __restrict__ Wvh,
    const float* __restrict__ bq, const float* __restrict__ bk,
    const float* __restrict__ bv, _Float16* __restrict__ Qh,
    _Float16* __restrict__ Kh, _Float16* __restrict__ VT) {
  __shared__ _Float16 lds[65536];
  const int tid = threadIdx.x;
  const int bid = blockIdx.x;
  const int swz = (bid & 7) * 96 + (bid >> 3);  // XCD swizzle, 768%8==0
  const int mt = swz / 12, nt = swz % 12;
  const int sel = nt >> 2;
  const _Float16* Wsel = sel == 0 ? Wqh : (sel == 1 ? Wkh : Wvh);
  const float* bsel = sel == 0 ? bq : (sel == 1 ? bk : bv);
  const _Float16* Ab = xh + (size_t)mt * 256 * 1024;
  const _Float16* Bb = Wsel + (size_t)(nt & 3) * 256 * 1024;
  f32x4 acc[8][4] = {};
  auto ga = [&](int t, int h) { return Ab + (size_t)h * 128 * 1024 + t * 64; };
  auto gb = [&](int t, int h) { return Bb + (size_t)h * 128 * 1024 + t * 64; };
  gemm_core<1024, 1024>(ga, gb, 16, (char*)lds, tid, acc);
  const int l = tid & 63, w = tid >> 6;
  const int wm = w >> 2, wn = w & 3;
  const int lr = l & 15, lk = l >> 4;
  const int n0 = (nt & 3) * 256;
  __syncthreads();
  // acc -> LDS f16 (rotated layout), then coalesced 16B stores
#pragma unroll
  for (int ai = 0; ai < 8; ++ai) {
    const int rbase = wm * 128 + (ai >> 2) * 64 + (ai & 3) * 16 + lk * 4;
#pragma unroll
    for (int j = 0; j < 4; ++j) {
      const int col = wn * 64 + j * 16 + lr;
      const float bvv = bsel[n0 + col];
#pragma unroll
      for (int r = 0; r < 4; ++r) {
        const int row = rbase + r;
        const float v = acc[ai][j][r] + bvv;
        if (sel < 2)
          lds[row * 256 + ((col + (row >> 2) * 16) & 255)] = (_Float16)v;
        else
          lds[col * 256 + ((row + (col >> 2) * 16) & 255)] = (_Float16)v;
      }
    }
  }
  __syncthreads();
#pragma unroll
  for (int i = 0; i < 16; ++i) {
    const int c = i * 512 + tid;
    const int row = c >> 5, c8 = c & 31;
    half8 v = *(const half8*)&lds[row * 256 + ((c8 * 8 + (row >> 2) * 16) & 255)];
    if (sel < 2) {
      _Float16* Out = sel == 0 ? Qh : Kh;
      *(half8*)&Out[(size_t)(mt * 256 + row) * 1024 + n0 + c8 * 8] = v;
    } else {
      const int bb = mt >> 3, t0 = (mt & 7) * 256;
      *(half8*)&VT[((size_t)bb * 1024 + n0 + row) * 2048 + t0 + c8 * 8] = v;
    }
  }
}

// Causal QK^T: blockIdx.x = tri tile (qt,jt<=qt) of 256^2 -> compact f32 S
// [b][tri36][256][256], scaled, -inf above diagonal.
__global__ __launch_bounds__(512, 2) void gemm_qk(const _Float16* __restrict__ Qh,
                                                  const _Float16* __restrict__ Kh,
                                                  float* __restrict__ Sc) {
  __shared__ _Float16 lds[65536];
  const int tid = threadIdx.x;
  const int idx = blockIdx.x, bb = blockIdx.y;
  int qt = 0;
  while ((qt + 1) * (qt + 2) / 2 <= idx) ++qt;
  const int jt = idx - qt * (qt + 1) / 2;
  const _Float16* Ab = Qh + ((size_t)bb * 2048 + qt * 256) * 1024;
  const _Float16* Bb = Kh + ((size_t)bb * 2048 + jt * 256) * 1024;
  f32x4 acc[8][4] = {};
  auto ga = [&](int t, int h) { return Ab + (size_t)h * 128 * 1024 + t * 64; };
  auto gb = [&](int t, int h) { return Bb + (size_t)h * 128 * 1024 + t * 64; };
  gemm_core<1024, 1024>(ga, gb, 16, (char*)lds, tid, acc);
  const int l = tid & 63, w = tid >> 6;
  const int wm = w >> 2, wn = w & 3;
  const int lr = l & 15, lk = l >> 4;
  float* St = Sc + ((size_t)bb * 36 + idx) * 65536;
  const float NINF = -__builtin_inff();
#pragma unroll
  for (int ai = 0; ai < 8; ++ai) {
    const int rbase = wm * 128 + (ai >> 2) * 64 + (ai & 3) * 16 + lk * 4;
#pragma unroll
    for (int j = 0; j < 4; ++j) {
      const int ck = wn * 64 + j * 16 + lr;
      const int kg = jt * 256 + ck;
#pragma unroll
      for (int r = 0; r < 4; ++r) {
        const int rq = rbase + r;
        const int qg = qt * 256 + rq;
        St[(size_t)rq * 256 + ck] = (kg <= qg) ? acc[ai][j][r] * ATT_SCALE : NINF;
      }
    }
  }
}

// One wave per row: in-register softmax over compact S row, writes f16 P.
__global__ __launch_bounds__(256) void softmax_p(const float* __restrict__ Sc,
                                                 _Float16* __restrict__ Pc) {
  const int l = threadIdx.x & 63;
  const int gid = blockIdx.x * 4 + (threadIdx.x >> 6);
  const int b = gid >> 11, q = gid & 2047;
  const int qt = q >> 8, rq = q & 255;
  const int ntile = qt + 1;
  const size_t base = ((size_t)b * 36 + (size_t)(qt * (qt + 1) / 2)) * 65536 +
                      (size_t)rq * 256 + l * 4;
  float vx[32];
  float m = -__builtin_inff();
#pragma unroll
  for (int c = 0; c < 8; ++c) {
    float4 t = {-__builtin_inff(), -__builtin_inff(), -__builtin_inff(), -__builtin_inff()};
    if (c < ntile) t = *(const float4*)&Sc[base + (size_t)c * 65536];
    vx[4 * c] = t.x; vx[4 * c + 1] = t.y; vx[4 * c + 2] = t.z; vx[4 * c + 3] = t.w;
    m = fmaxf(m, fmaxf(fmaxf(t.x, t.y), fmaxf(t.z, t.w)));
  }
#pragma unroll
  for (int s = 1; s < 64; s <<= 1) m = fmaxf(m, __shfl_xor(m, s, 64));
  float sum = 0.f;
#pragma unroll
  for (int i = 0; i < 32; ++i) { vx[i] = __expf(vx[i] - m); sum += vx[i]; }
#pragma unroll
  for (int s = 1; s < 64; s <<= 1) sum += __shfl_xor(sum, s, 64);
  const float inv = 1.f / sum;
  _Float16* Pb = Pc + base;
#pragma unroll
  for (int c = 0; c < 8; ++c) {
    if (c < ntile) {
      _Float16 tmp[4];
      tmp[0] = (_Float16)(vx[4 * c] * inv);
      tmp[1] = (_Float16)(vx[4 * c + 1] * inv);
      tmp[2] = (_Float16)(vx[4 * c + 2] * inv);
      tmp[3] = (_Float16)(vx[4 * c + 3] * inv);
      *(uint64_t*)&Pb[(size_t)c * 65536] = *(const uint64_t*)tmp;
    }
  }
}

// O[b,q,d] = sum_k P[b,q,k]*VT[b,d,k], causal k range per q-tile.
__global__ __launch_bounds__(512, 2) void gemm_pv(const _Float16* __restrict__ Pc,
                                                  const _Float16* __restrict__ VT,
                                                  float* __restrict__ O) {
  __shared__ _Float16 lds[65536];
  const int tid = threadIdx.x;
  const int dt = blockIdx.x, qt = 7 - blockIdx.y, b = blockIdx.z;
  const _Float16* Pb = Pc + ((size_t)b * 36 + (size_t)(qt * (qt + 1) / 2)) * 65536;
  const _Float16* Vb = VT + ((size_t)b * 1024 + dt * 256) * 2048;
  f32x4 acc[8][4] = {};
  auto ga = [&](int t, int h) {
    return Pb + (size_t)(t >> 2) * 65536 + (size_t)h * 128 * 256 + (t & 3) * 64;
  };
  auto gb = [&](int t, int h) { return Vb + (size_t)h * 128 * 2048 + t * 64; };
  gemm_core<256, 2048>(ga, gb, (qt + 1) * 4, (char*)lds, tid, acc);
  const int l = tid & 63, w = tid >> 6;
  const int wm = w >> 2, wn = w & 3;
  const int lr = l & 15, lk = l >> 4;
#pragma unroll
  for (int ai = 0; ai < 8; ++ai) {
    const int rbase = qt * 256 + wm * 128 + (ai >> 2) * 64 + (ai & 3) * 16 + lk * 4;
#pragma unroll
    for (int j = 0; j < 4; ++j) {
      const int cg = dt * 256 + wn * 64 + j * 16 + lr;
#pragma unroll
      for (int r = 0; r < 4; ++r)
        O[((size_t)b * 2048 + rbase + r) * 1024 + cg] = acc[ai][j][r];
    }
  }
}

extern "C" void kernel_launch(void* const* d_in, const int* in_sizes, int n_in,
                              void* d_out, int out_size, void* d_ws, size_t ws_size,
                              hipStream_t stream) {
  const float* x    = (const float*)d_in[0];
  const float* Wq_w = (const float*)d_in[1];
  const float* Wq_b = (const float*)d_in[2];
  const float* Wk_w = (const float*)d_in[3];
  const float* Wk_b = (const float*)d_in[4];
  const float* Wv_w = (const float*)d_in[5];
  const float* Wv_b = (const float*)d_in[6];
  float* out = (float*)d_out;
  char* ws = (char*)d_ws;
  _Float16* xh  = (_Float16*)(ws);              // 32 MiB (dead after proj)
  _Float16* Wqh = (_Float16*)(ws + 33554432);   // 2 MiB
  _Float16* Wkh = (_Float16*)(ws + 35651584);   // 2 MiB
  _Float16* Wvh = (_Float16*)(ws + 37748736);   // 2 MiB
  float*    Sc  = (float*)(ws);                 // compact tri S f32 (aliases xh+W)
  _Float16* Qh  = (_Float16*)(ws + 75497472);   // 32 MiB
  _Float16* Kh  = (_Float16*)(ws + 109051904);  // 32 MiB
  _Float16* Pc  = (_Float16*)(ws + 75497472);   // compact tri P f16 (aliases Q/K)
  _Float16* VT  = (_Float16*)(ws + 142606336);  // 32 MiB

  cvt_f32_f16<<<8192, 256, 0, stream>>>(x, xh, 2097152);
  cvt_f32_f16<<<512, 256, 0, stream>>>(Wq_w, Wqh, 131072);
  cvt_f32_f16<<<512, 256, 0, stream>>>(Wk_w, Wkh, 131072);
  cvt_f32_f16<<<512, 256, 0, stream>>>(Wv_w, Wvh, 131072);
  gemm_qkv<<<768, 512, 0, stream>>>(xh, Wqh, Wkh, Wvh, Wq_b, Wk_b, Wv_b, Qh, Kh, VT);
  gemm_qk<<<dim3(36, 8), 512, 0, stream>>>(Qh, Kh, Sc);
  softmax_p<<<4096, 256, 0, stream>>>(Sc, Pc);
  gemm_pv<<<dim3(4, 8, 8), 512, 0, stream>>>(Pc, VT, out);
}

// Round 8
// 283.771 us; speedup vs baseline: 1.1315x; 1.0386x over previous
//
#include <hip/hip_runtime.h>

// ScaledAttention B=8,T=2048,D=1024 single-head, SCALE=1/8.
// cvt f32->f16 (single fused launch) -> fused QKV proj -> causal QK^T
// (compact f32 S) -> row softmax -> PV. GEMM core: 256x256 tile, BK=64,
// 8 waves (2Mx4N), [128][64] f16 half-tiles, chunk-XOR (row&7) swizzle.
// R8: ONE barrier per phase (hazard-checked at wave-skew<=1), fragment
// prefetch one phase ahead (compiler-counted lgkm waits), vmcnt(2)/K-tile.

typedef float f32x4 __attribute__((ext_vector_type(4)));
typedef _Float16 half8 __attribute__((ext_vector_type(8)));

#define DEVINL __device__ __forceinline__
static constexpr float ATT_SCALE = 0.125f;  // 1/sqrt(1024/16)

DEVINL void gload_lds16(const _Float16* g, _Float16* l) {
  __builtin_amdgcn_global_load_lds((const __attribute__((address_space(1))) void*)g,
                                   (__attribute__((address_space(3))) void*)l, 16, 0, 0);
}

#define SBAR() __builtin_amdgcn_sched_barrier(0)
#define MM(AOFF, BOFF, ASET, BSET) \
  _Pragma("unroll") for (int kk_ = 0; kk_ < 2; ++kk_) \
  _Pragma("unroll") for (int i_ = 0; i_ < 4; ++i_) \
  _Pragma("unroll") for (int jj_ = 0; jj_ < 2; ++jj_) \
    acc[(AOFF) + i_][(BOFF) + jj_] = __builtin_amdgcn_mfma_f32_16x16x32_f16( \
        ASET[i_][kk_], BSET[jj_][kk_], acc[(AOFF) + i_][(BOFF) + jj_], 0, 0, 0);
#define PH_BAR() SBAR(); __builtin_amdgcn_s_barrier(); \
    __builtin_amdgcn_s_setprio(1)
#define PH_DONE() __builtin_amdgcn_s_setprio(0); SBAR()

// LDS map (bytes): buf b at b*65536: A-half0@0 A-half1@16384 B-half0@32768
// B-half1@49152. Half-tile = [128 rows][64 cols] f16; element (r, 16B-chunk c)
// stored at physical chunk c ^ (r&7).
template <int LDA, int LDB, class GA, class GB>
DEVINL void gemm_core(GA ga, GB gb, int NT, char* ldsb, int tid, f32x4 acc[8][4]) {
  const int l = tid & 63, w = tid >> 6;
  const int wm = w >> 2, wn = w & 3;
  const int lr = l & 15, lk = l >> 4;
  int srow[2], scol[2];
#pragma unroll
  for (int i = 0; i < 2; ++i) {
    const int P = i * 512 + w * 64 + l;
    srow[i] = P >> 3;
    scol[i] = (P & 7) ^ (srow[i] & 7);
  }
  const int ch0 = ((lk ^ (lr & 7)) << 4);
  const int ch1 = (((lk + 4) ^ (lr & 7)) << 4);
  const int abase = lr * 128;
  const int bbase = (wn & 1) * 8192 + lr * 128;

  half8 aA[4][2], aB[4][2], bA[2][2], bB[2][2];

  auto STGA = [&](int t, int h, int bufb) {
    const _Float16* g0 = ga(t, h);
    char* dst = ldsb + bufb * 65536 + h * 16384;
#pragma unroll
    for (int i = 0; i < 2; ++i)
      gload_lds16(g0 + (size_t)srow[i] * LDA + scol[i] * 8,
                  (_Float16*)(dst + i * 8192 + w * 1024));
  };
  auto STGB = [&](int t, int h, int bufb) {
    const _Float16* g0 = gb(t, h);
    char* dst = ldsb + bufb * 65536 + 32768 + h * 16384;
#pragma unroll
    for (int i = 0; i < 2; ++i)
      gload_lds16(g0 + (size_t)srow[i] * LDB + scol[i] * 8,
                  (_Float16*)(dst + i * 8192 + w * 1024));
  };
  auto RDA = [&](int bufb, int ih, half8 d[4][2]) {
    const char* sA = ldsb + bufb * 65536 + wm * 16384 + ih * 8192;
#pragma unroll
    for (int i = 0; i < 4; ++i) {
      d[i][0] = *(const half8*)(sA + abase + i * 2048 + ch0);
      d[i][1] = *(const half8*)(sA + abase + i * 2048 + ch1);
    }
  };
  auto RDB = [&](int bufb, int jh, half8 d[2][2]) {
    const char* sB = ldsb + bufb * 65536 + 32768 + (wn >> 1) * 16384 + jh * 4096;
#pragma unroll
    for (int jj = 0; jj < 2; ++jj) {
      d[jj][0] = *(const half8*)(sB + bbase + jj * 2048 + ch0);
      d[jj][1] = *(const half8*)(sB + bbase + jj * 2048 + ch1);
    }
  };

  // Per tile t (1 barrier/phase; reads are for the NEXT phase's MFMA):
  //  P0: issue bB=B1(t) | stage A0(t+1)->obuf | bar | MM(aA,bA)
  //  P1: issue aB=A1(t) | stage A1(t+1)->obuf | bar | MM(aA,bB)
  //  P2: stage B0(t+2)->bufb | vmcnt(2) | bar | MM(aB,bA)
  //  P3: issue aA=A0(t+1),bA=B0(t+1) | stage B1(t+2)->bufb | bar | MM(aB,bB)
  auto tile = [&](int t, bool stA, bool stB) {
    const int bufb = t & 1, obuf = bufb ^ 1;
    // P0
    RDB(bufb, 1, bB);
    if (stA) STGA(t + 1, 0, obuf);
    PH_BAR(); MM(0, 0, aA, bA); PH_DONE();
    // P1
    RDA(bufb, 1, aB);
    if (stA) STGA(t + 1, 1, obuf);
    PH_BAR(); MM(0, 2, aA, bB); PH_DONE();
    // P2
    if (stB) STGB(t + 2, 0, bufb);
    SBAR();
    if (stB)      { asm volatile("s_waitcnt vmcnt(2)" ::: "memory"); }
    else if (stA) { asm volatile("s_waitcnt vmcnt(0)" ::: "memory"); }
    PH_BAR(); MM(4, 0, aB, bA); PH_DONE();
    // P3
    if (stA) { RDA(obuf, 0, aA); RDB(obuf, 0, bA); }
    if (stB) STGB(t + 2, 1, bufb);
    PH_BAR(); MM(4, 2, aB, bB); PH_DONE();
  };

  // prologue: tile0 (A0,A1,B0,B1) + tile1 (B0,B1); wait tile0; preload frags
  STGA(0, 0, 0); STGA(0, 1, 0); STGB(0, 0, 0); STGB(0, 1, 0);
  STGB(1, 0, 1); STGB(1, 1, 1);
  asm volatile("s_waitcnt vmcnt(4)" ::: "memory");
  __builtin_amdgcn_s_barrier(); SBAR();
  RDA(0, 0, aA); RDB(0, 0, bA);
  for (int t = 0; t < NT - 2; ++t) tile(t, true, true);
  tile(NT - 2, true, false);
  tile(NT - 1, false, false);
}

// Fused cvt: x (2097152 groups of 8), then Wq/Wk/Wv (131072 groups each).
__global__ __launch_bounds__(256) void cvt_all(const float* __restrict__ x,
                                               const float* __restrict__ wq,
                                               const float* __restrict__ wk,
                                               const float* __restrict__ wv,
                                               _Float16* __restrict__ xh,
                                               _Float16* __restrict__ wqh,
                                               _Float16* __restrict__ wkh,
                                               _Float16* __restrict__ wvh) {
  const int n8 = 2490368;  // total half8 groups
  for (int i = blockIdx.x * 256 + threadIdx.x; i < n8; i += 2048 * 256) {
    const float* src; _Float16* dst; int off;
    if (i < 2097152)      { src = x;  dst = xh;  off = i; }
    else if (i < 2228224) { src = wq; dst = wqh; off = i - 2097152; }
    else if (i < 2359296) { src = wk; dst = wkh; off = i - 2228224; }
    else                  { src = wv; dst = wvh; off = i - 2359296; }
    const float4* p = (const float4*)src + (size_t)off * 2;
    float4 v0 = p[0], v1 = p[1];
    half8 h;
    h[0] = (_Float16)v0.x; h[1] = (_Float16)v0.y; h[2] = (_Float16)v0.z; h[3] = (_Float16)v0.w;
    h[4] = (_Float16)v1.x; h[5] = (_Float16)v1.y; h[6] = (_Float16)v1.z; h[7] = (_Float16)v1.w;
    *((half8*)dst + off) = h;
  }
}

// Fused QKV: C[m,n]=sum_k x[m,k]W[n,k]+b[n], M=16384, N=3072, K=1024.
__global__ __launch_bounds__(512) void gemm_qkv(
    const _Float16* __restrict__ xh, const _Float16* __restrict__ Wqh,
    const _Float16* __restrict__ Wkh, const _Float16* __restrict__ Wvh,
    const float* __restrict__ bq, const float* __restrict__ bk,
    const float* __restrict__ bv, _Float16* __restrict__ Qh,
    _Float16* __restrict__ Kh, _Float16* __restrict__ VT) {
  __shared__ _Float16 lds[65536];
  const int tid = threadIdx.x;
  const int bid = blockIdx.x;
  const int swz = (bid & 7) * 96 + (bid >> 3);  // XCD swizzle, 768%8==0
  const int mt = swz / 12, nt = swz % 12;
  const int sel = nt >> 2;
  const _Float16* Wsel = sel == 0 ? Wqh : (sel == 1 ? Wkh : Wvh);
  const float* bsel = sel == 0 ? bq : (sel == 1 ? bk : bv);
  const _Float16* Ab = xh + (size_t)mt * 256 * 1024;
  const _Float16* Bb = Wsel + (size_t)(nt & 3) * 256 * 1024;
  f32x4 acc[8][4] = {};
  auto ga = [&](int t, int h) { return Ab + (size_t)h * 128 * 1024 + t * 64; };
  auto gb = [&](int t, int h) { return Bb + (size_t)h * 128 * 1024 + t * 64; };
  gemm_core<1024, 1024>(ga, gb, 16, (char*)lds, tid, acc);
  const int l = tid & 63, w = tid >> 6;
  const int wm = w >> 2, wn = w & 3;
  const int lr = l & 15, lk = l >> 4;
  const int n0 = (nt & 3) * 256;
  __syncthreads();
  // acc -> LDS f16 (rotated layout), then coalesced 16B stores
#pragma unroll
  for (int ai = 0; ai < 8; ++ai) {
    const int rbase = wm * 128 + (ai >> 2) * 64 + (ai & 3) * 16 + lk * 4;
#pragma unroll
    for (int j = 0; j < 4; ++j) {
      const int col = wn * 64 + j * 16 + lr;
      const float bvv = bsel[n0 + col];
#pragma unroll
      for (int r = 0; r < 4; ++r) {
        const int row = rbase + r;
        const float v = acc[ai][j][r] + bvv;
        if (sel < 2)
          lds[row * 256 + ((col + (row >> 2) * 16) & 255)] = (_Float16)v;
        else
          lds[col * 256 + ((row + (col >> 2) * 16) & 255)] = (_Float16)v;
      }
    }
  }
  __syncthreads();
#pragma unroll
  for (int i = 0; i < 16; ++i) {
    const int c = i * 512 + tid;
    const int row = c >> 5, c8 = c & 31;
    half8 v = *(const half8*)&lds[row * 256 + ((c8 * 8 + (row >> 2) * 16) & 255)];
    if (sel < 2) {
      _Float16* Out = sel == 0 ? Qh : Kh;
      *(half8*)&Out[(size_t)(mt * 256 + row) * 1024 + n0 + c8 * 8] = v;
    } else {
      const int bb = mt >> 3, t0 = (mt & 7) * 256;
      *(half8*)&VT[((size_t)bb * 1024 + n0 + row) * 2048 + t0 + c8 * 8] = v;
    }
  }
}

// Causal QK^T: blockIdx.x = tri tile (qt,jt<=qt) of 256^2 -> compact f32 S
// [b][tri36][256][256], scaled, -inf above diagonal.
__global__ __launch_bounds__(512) void gemm_qk(const _Float16* __restrict__ Qh,
                                               const _Float16* __restrict__ Kh,
                                               float* __restrict__ Sc) {
  __shared__ _Float16 lds[65536];
  const int tid = threadIdx.x;
  const int idx = blockIdx.x, bb = blockIdx.y;
  int qt = 0;
  while ((qt + 1) * (qt + 2) / 2 <= idx) ++qt;
  const int jt = idx - qt * (qt + 1) / 2;
  const _Float16* Ab = Qh + ((size_t)bb * 2048 + qt * 256) * 1024;
  const _Float16* Bb = Kh + ((size_t)bb * 2048 + jt * 256) * 1024;
  f32x4 acc[8][4] = {};
  auto ga = [&](int t, int h) { return Ab + (size_t)h * 128 * 1024 + t * 64; };
  auto gb = [&](int t, int h) { return Bb + (size_t)h * 128 * 1024 + t * 64; };
  gemm_core<1024, 1024>(ga, gb, 16, (char*)lds, tid, acc);
  const int l = tid & 63, w = tid >> 6;
  const int wm = w >> 2, wn = w & 3;
  const int lr = l & 15, lk = l >> 4;
  float* St = Sc + ((size_t)bb * 36 + idx) * 65536;
  const float NINF = -__builtin_inff();
#pragma unroll
  for (int ai = 0; ai < 8; ++ai) {
    const int rbase = wm * 128 + (ai >> 2) * 64 + (ai & 3) * 16 + lk * 4;
#pragma unroll
    for (int j = 0; j < 4; ++j) {
      const int ck = wn * 64 + j * 16 + lr;
      const int kg = jt * 256 + ck;
#pragma unroll
      for (int r = 0; r < 4; ++r) {
        const int rq = rbase + r;
        const int qg = qt * 256 + rq;
        St[(size_t)rq * 256 + ck] = (kg <= qg) ? acc[ai][j][r] * ATT_SCALE : NINF;
      }
    }
  }
}

// One wave per row: in-register softmax over compact S row, writes f16 P.
__global__ __launch_bounds__(256) void softmax_p(const float* __restrict__ Sc,
                                                 _Float16* __restrict__ Pc) {
  const int l = threadIdx.x & 63;
  const int gid = blockIdx.x * 4 + (threadIdx.x >> 6);
  const int b = gid >> 11, q = gid & 2047;
  const int qt = q >> 8, rq = q & 255;
  const int ntile = qt + 1;
  const size_t base = ((size_t)b * 36 + (size_t)(qt * (qt + 1) / 2)) * 65536 +
                      (size_t)rq * 256 + l * 4;
  float vx[32];
  float m = -__builtin_inff();
#pragma unroll
  for (int c = 0; c < 8; ++c) {
    float4 t = {-__builtin_inff(), -__builtin_inff(), -__builtin_inff(), -__builtin_inff()};
    if (c < ntile) t = *(const float4*)&Sc[base + (size_t)c * 65536];
    vx[4 * c] = t.x; vx[4 * c + 1] = t.y; vx[4 * c + 2] = t.z; vx[4 * c + 3] = t.w;
    m = fmaxf(m, fmaxf(fmaxf(t.x, t.y), fmaxf(t.z, t.w)));
  }
#pragma unroll
  for (int s = 1; s < 64; s <<= 1) m = fmaxf(m, __shfl_xor(m, s, 64));
  float sum = 0.f;
#pragma unroll
  for (int i = 0; i < 32; ++i) { vx[i] = __expf(vx[i] - m); sum += vx[i]; }
#pragma unroll
  for (int s = 1; s < 64; s <<= 1) sum += __shfl_xor(sum, s, 64);
  const float inv = 1.f / sum;
  _Float16* Pb = Pc + base;
#pragma unroll
  for (int c = 0; c < 8; ++c) {
    if (c < ntile) {
      _Float16 tmp[4];
      tmp[0] = (_Float16)(vx[4 * c] * inv);
      tmp[1] = (_Float16)(vx[4 * c + 1] * inv);
      tmp[2] = (_Float16)(vx[4 * c + 2] * inv);
      tmp[3] = (_Float16)(vx[4 * c + 3] * inv);
      *(uint64_t*)&Pb[(size_t)c * 65536] = *(const uint64_t*)tmp;
    }
  }
}

// O[b,q,d] = sum_k P[b,q,k]*VT[b,d,k], causal k range per q-tile.
__global__ __launch_bounds__(512) void gemm_pv(const _Float16* __restrict__ Pc,
                                               const _Float16* __restrict__ VT,
                                               float* __restrict__ O) {
  __shared__ _Float16 lds[65536];
  const int tid = threadIdx.x;
  const int dt = blockIdx.x, qt = 7 - blockIdx.y, b = blockIdx.z;
  const _Float16* Pb = Pc + ((size_t)b * 36 + (size_t)(qt * (qt + 1) / 2)) * 65536;
  const _Float16* Vb = VT + ((size_t)b * 1024 + dt * 256) * 2048;
  f32x4 acc[8][4] = {};
  auto ga = [&](int t, int h) {
    return Pb + (size_t)(t >> 2) * 65536 + (size_t)h * 128 * 256 + (t & 3) * 64;
  };
  auto gb = [&](int t, int h) { return Vb + (size_t)h * 128 * 2048 + t * 64; };
  gemm_core<256, 2048>(ga, gb, (qt + 1) * 4, (char*)lds, tid, acc);
  const int l = tid & 63, w = tid >> 6;
  const int wm = w >> 2, wn = w & 3;
  const int lr = l & 15, lk = l >> 4;
#pragma unroll
  for (int ai = 0; ai < 8; ++ai) {
    const int rbase = qt * 256 + wm * 128 + (ai >> 2) * 64 + (ai & 3) * 16 + lk * 4;
#pragma unroll
    for (int j = 0; j < 4; ++j) {
      const int cg = dt * 256 + wn * 64 + j * 16 + lr;
#pragma unroll
      for (int r = 0; r < 4; ++r)
        O[((size_t)b * 2048 + rbase + r) * 1024 + cg] = acc[ai][j][r];
    }
  }
}

extern "C" void kernel_launch(void* const* d_in, const int* in_sizes, int n_in,
                              void* d_out, int out_size, void* d_ws, size_t ws_size,
                              hipStream_t stream) {
  const float* x    = (const float*)d_in[0];
  const float* Wq_w = (const float*)d_in[1];
  const float* Wq_b = (const float*)d_in[2];
  const float* Wk_w = (const float*)d_in[3];
  const float* Wk_b = (const float*)d_in[4];
  const float* Wv_w = (const float*)d_in[5];
  const float* Wv_b = (const float*)d_in[6];
  float* out = (float*)d_out;
  char* ws = (char*)d_ws;
  _Float16* xh  = (_Float16*)(ws);              // 32 MiB (dead after proj)
  _Float16* Wqh = (_Float16*)(ws + 33554432);   // 2 MiB
  _Float16* Wkh = (_Float16*)(ws + 35651584);   // 2 MiB
  _Float16* Wvh = (_Float16*)(ws + 37748736);   // 2 MiB
  float*    Sc  = (float*)(ws);                 // compact tri S f32 (aliases xh+W)
  _Float16* Qh  = (_Float16*)(ws + 75497472);   // 32 MiB
  _Float16* Kh  = (_Float16*)(ws + 109051904);  // 32 MiB
  _Float16* Pc  = (_Float16*)(ws + 75497472);   // compact tri P f16 (aliases Q/K)
  _Float16* VT  = (_Float16*)(ws + 142606336);  // 32 MiB

  cvt_all<<<2048, 256, 0, stream>>>(x, Wq_w, Wk_w, Wv_w, xh, Wqh, Wkh, Wvh);
  gemm_qkv<<<768, 512, 0, stream>>>(xh, Wqh, Wkh, Wvh, Wq_b, Wk_b, Wv_b, Qh, Kh, VT);
  gemm_qk<<<dim3(36, 8), 512, 0, stream>>>(Qh, Kh, Sc);
  softmax_p<<<4096, 256, 0, stream>>>(Sc, Pc);
  gemm_pv<<<dim3(4, 8, 8), 512, 0, stream>>>(Pc, VT, out);
}

// Round 9
// 275.362 us; speedup vs baseline: 1.1660x; 1.0305x over previous
//
#include <hip/hip_runtime.h>

// ScaledAttention B=8,T=2048,D=1024 single-head, SCALE=1/8.
// cvt f32->f16 -> fused QKV proj (256x256 8-phase core) -> causal QK^T
// (256x128 core, 576 uniform jobs, f16 S) -> row softmax (f16 S) ->
// PV (256x128 core, 512 LPT-ordered jobs).

typedef float f32x4 __attribute__((ext_vector_type(4)));
typedef _Float16 half8 __attribute__((ext_vector_type(8)));
typedef _Float16 half4 __attribute__((ext_vector_type(4)));

#define DEVINL __device__ __forceinline__
static constexpr float ATT_SCALE = 0.125f;  // 1/sqrt(1024/16)

DEVINL void gload_lds16(const _Float16* g, _Float16* l) {
  __builtin_amdgcn_global_load_lds((const __attribute__((address_space(1))) void*)g,
                                   (__attribute__((address_space(3))) void*)l, 16, 0, 0);
}

#define SBAR() __builtin_amdgcn_sched_barrier(0)

// ------------------------- 256x256 core (qkv) ------------------------------
#define MM(AOFF, BOFF, ASET, BSET) \
  _Pragma("unroll") for (int kk_ = 0; kk_ < 2; ++kk_) \
  _Pragma("unroll") for (int i_ = 0; i_ < 4; ++i_) \
  _Pragma("unroll") for (int jj_ = 0; jj_ < 2; ++jj_) \
    acc[(AOFF) + i_][(BOFF) + jj_] = __builtin_amdgcn_mfma_f32_16x16x32_f16( \
        ASET[i_][kk_], BSET[jj_][kk_], acc[(AOFF) + i_][(BOFF) + jj_], 0, 0, 0);
#define PH_BAR() SBAR(); __builtin_amdgcn_s_barrier(); \
    __builtin_amdgcn_s_setprio(1)
#define PH_DONE() __builtin_amdgcn_s_setprio(0); SBAR()

template <int LDA, int LDB, class GA, class GB>
DEVINL void gemm_core(GA ga, GB gb, int NT, char* ldsb, int tid, f32x4 acc[8][4]) {
  const int l = tid & 63, w = tid >> 6;
  const int wm = w >> 2, wn = w & 3;
  const int lr = l & 15, lk = l >> 4;
  int srow[2], scol[2];
#pragma unroll
  for (int i = 0; i < 2; ++i) {
    const int P = i * 512 + w * 64 + l;
    srow[i] = P >> 3;
    scol[i] = (P & 7) ^ (srow[i] & 7);
  }
  const int ch0 = ((lk ^ (lr & 7)) << 4);
  const int ch1 = (((lk + 4) ^ (lr & 7)) << 4);
  const int abase = lr * 128;
  const int bbase = (wn & 1) * 8192 + lr * 128;

  half8 aA[4][2], aB[4][2], bA[2][2], bB[2][2];

  auto STGA = [&](int t, int h, int bufb) {
    const _Float16* g0 = ga(t, h);
    char* dst = ldsb + bufb * 65536 + h * 16384;
#pragma unroll
    for (int i = 0; i < 2; ++i)
      gload_lds16(g0 + (size_t)srow[i] * LDA + scol[i] * 8,
                  (_Float16*)(dst + i * 8192 + w * 1024));
  };
  auto STGB = [&](int t, int h, int bufb) {
    const _Float16* g0 = gb(t, h);
    char* dst = ldsb + bufb * 65536 + 32768 + h * 16384;
#pragma unroll
    for (int i = 0; i < 2; ++i)
      gload_lds16(g0 + (size_t)srow[i] * LDB + scol[i] * 8,
                  (_Float16*)(dst + i * 8192 + w * 1024));
  };
  auto RDA = [&](int bufb, int ih, half8 d[4][2]) {
    const char* sA = ldsb + bufb * 65536 + wm * 16384 + ih * 8192;
#pragma unroll
    for (int i = 0; i < 4; ++i) {
      d[i][0] = *(const half8*)(sA + abase + i * 2048 + ch0);
      d[i][1] = *(const half8*)(sA + abase + i * 2048 + ch1);
    }
  };
  auto RDB = [&](int bufb, int jh, half8 d[2][2]) {
    const char* sB = ldsb + bufb * 65536 + 32768 + (wn >> 1) * 16384 + jh * 4096;
#pragma unroll
    for (int jj = 0; jj < 2; ++jj) {
      d[jj][0] = *(const half8*)(sB + bbase + jj * 2048 + ch0);
      d[jj][1] = *(const half8*)(sB + bbase + jj * 2048 + ch1);
    }
  };

  auto tile = [&](int t, bool stA, bool stB) {
    const int bufb = t & 1, obuf = bufb ^ 1;
    RDB(bufb, 1, bB);
    if (stA) STGA(t + 1, 0, obuf);
    PH_BAR(); MM(0, 0, aA, bA); PH_DONE();
    RDA(bufb, 1, aB);
    if (stA) STGA(t + 1, 1, obuf);
    PH_BAR(); MM(0, 2, aA, bB); PH_DONE();
    if (stB) STGB(t + 2, 0, bufb);
    SBAR();
    if (stB)      { asm volatile("s_waitcnt vmcnt(2)" ::: "memory"); }
    else if (stA) { asm volatile("s_waitcnt vmcnt(0)" ::: "memory"); }
    PH_BAR(); MM(4, 0, aB, bA); PH_DONE();
    if (stA) { RDA(obuf, 0, aA); RDB(obuf, 0, bA); }
    if (stB) STGB(t + 2, 1, bufb);
    PH_BAR(); MM(4, 2, aB, bB); PH_DONE();
  };

  STGA(0, 0, 0); STGA(0, 1, 0); STGB(0, 0, 0); STGB(0, 1, 0);
  STGB(1, 0, 1); STGB(1, 1, 1);
  asm volatile("s_waitcnt vmcnt(4)" ::: "memory");
  __builtin_amdgcn_s_barrier(); SBAR();
  RDA(0, 0, aA); RDB(0, 0, bA);
  for (int t = 0; t < NT - 2; ++t) tile(t, true, true);
  tile(NT - 2, true, false);
  tile(NT - 1, false, false);
}

// ------------------- 256x128 core (qk, pv) ---------------------------------
// 8 waves as 4M x 2N, wave-tile 64x64, acc[4][4]. BK=64.
// LDS per buf (49152 B): A-half0@0 A-half1@16384 B@32768; 2 bufs = 96 KB.
// Per K-tile: gap0 reads all 16 frags -> [bar, lgkm0, 16 MFMA kk0, bar] ->
// gap1 stages tile t+2 (safe: all reads of this buf drained at lgkm0),
// vmcnt(6) -> [bar, 16 MFMA kk1, bar].
template <int LDA, int LDB, class GA, class GB>
DEVINL void gemm_n128(GA ga, GB gb, int NT, char* ldsb, int tid, f32x4 acc[4][4]) {
  const int l = tid & 63, w = tid >> 6;
  const int wm = w >> 1, wn = w & 1;
  const int lr = l & 15, lk = l >> 4;
  int srow[2], scol[2];
#pragma unroll
  for (int i = 0; i < 2; ++i) {
    const int P = i * 512 + w * 64 + l;
    srow[i] = P >> 3;
    scol[i] = (P & 7) ^ (srow[i] & 7);
  }
  const int ch0 = ((lk ^ (lr & 7)) << 4);
  const int ch1 = (((lk + 4) ^ (lr & 7)) << 4);
  const int abase = (wm >> 1) * 16384 + ((wm & 1) * 64 + lr) * 128;
  const int bbase = 32768 + (wn * 64 + lr) * 128;

  auto STG = [&](const _Float16* g0, int ld, int bufb, int slot) {
    char* dst = ldsb + bufb * 49152 + slot * 16384;
#pragma unroll
    for (int i = 0; i < 2; ++i)
      gload_lds16(g0 + (size_t)srow[i] * ld + scol[i] * 8,
                  (_Float16*)(dst + i * 8192 + w * 1024));
  };
  half8 a[4][2], bfr[4][2];
  auto RD = [&](int bufb) {
    const char* bb = ldsb + bufb * 49152;
#pragma unroll
    for (int i = 0; i < 4; ++i) {
      a[i][0] = *(const half8*)(bb + abase + i * 2048 + ch0);
      a[i][1] = *(const half8*)(bb + abase + i * 2048 + ch1);
    }
#pragma unroll
    for (int j = 0; j < 4; ++j) {
      bfr[j][0] = *(const half8*)(bb + bbase + j * 2048 + ch0);
      bfr[j][1] = *(const half8*)(bb + bbase + j * 2048 + ch1);
    }
  };

  // prologue: tiles 0 and 1 (3 halves each = 6 loads each)
  STG(ga(0, 0), LDA, 0, 0); STG(ga(0, 1), LDA, 0, 1); STG(gb(0), LDB, 0, 2);
  STG(ga(1, 0), LDA, 1, 0); STG(ga(1, 1), LDA, 1, 1); STG(gb(1), LDB, 1, 2);
  asm volatile("s_waitcnt vmcnt(6)" ::: "memory");
  __builtin_amdgcn_s_barrier();

  for (int t = 0; t < NT; ++t) {
    const int bufb = t & 1;
    RD(bufb);
    SBAR();
    __builtin_amdgcn_s_barrier();
    asm volatile("s_waitcnt lgkmcnt(0)" ::: "memory");
    SBAR();
    __builtin_amdgcn_s_setprio(1);
#pragma unroll
    for (int i = 0; i < 4; ++i)
#pragma unroll
      for (int j = 0; j < 4; ++j)
        acc[i][j] = __builtin_amdgcn_mfma_f32_16x16x32_f16(a[i][0], bfr[j][0], acc[i][j], 0, 0, 0);
    __builtin_amdgcn_s_setprio(0);
    SBAR();
    __builtin_amdgcn_s_barrier();
    if (t + 2 < NT) {
      STG(ga(t + 2, 0), LDA, bufb, 0);
      STG(ga(t + 2, 1), LDA, bufb, 1);
      STG(gb(t + 2), LDB, bufb, 2);
      asm volatile("s_waitcnt vmcnt(6)" ::: "memory");
    } else if (t + 1 < NT) {
      asm volatile("s_waitcnt vmcnt(0)" ::: "memory");
    }
    SBAR();
    __builtin_amdgcn_s_barrier();
    __builtin_amdgcn_s_setprio(1);
#pragma unroll
    for (int i = 0; i < 4; ++i)
#pragma unroll
      for (int j = 0; j < 4; ++j)
        acc[i][j] = __builtin_amdgcn_mfma_f32_16x16x32_f16(a[i][1], bfr[j][1], acc[i][j], 0, 0, 0);
    __builtin_amdgcn_s_setprio(0);
    SBAR();
    __builtin_amdgcn_s_barrier();
  }
}

// ---------------------------------------------------------------------------
__global__ __launch_bounds__(256) void cvt_all(const float* __restrict__ x,
                                               const float* __restrict__ wq,
                                               const float* __restrict__ wk,
                                               const float* __restrict__ wv,
                                               _Float16* __restrict__ xh,
                                               _Float16* __restrict__ wqh,
                                               _Float16* __restrict__ wkh,
                                               _Float16* __restrict__ wvh) {
  const int n8 = 2490368;
  for (int i = blockIdx.x * 256 + threadIdx.x; i < n8; i += 2048 * 256) {
    const float* src; _Float16* dst; int off;
    if (i < 2097152)      { src = x;  dst = xh;  off = i; }
    else if (i < 2228224) { src = wq; dst = wqh; off = i - 2097152; }
    else if (i < 2359296) { src = wk; dst = wkh; off = i - 2228224; }
    else                  { src = wv; dst = wvh; off = i - 2359296; }
    const float4* p = (const float4*)src + (size_t)off * 2;
    float4 v0 = p[0], v1 = p[1];
    half8 h;
    h[0] = (_Float16)v0.x; h[1] = (_Float16)v0.y; h[2] = (_Float16)v0.z; h[3] = (_Float16)v0.w;
    h[4] = (_Float16)v1.x; h[5] = (_Float16)v1.y; h[6] = (_Float16)v1.z; h[7] = (_Float16)v1.w;
    *((half8*)dst + off) = h;
  }
}

// Fused QKV: C[m,n]=sum_k x[m,k]W[n,k]+b[n], M=16384, N=3072, K=1024.
__global__ __launch_bounds__(512) void gemm_qkv(
    const _Float16* __restrict__ xh, const _Float16* __restrict__ Wqh,
    const _Float16* __restrict__ Wkh, const _Float16* __restrict__ Wvh,
    const float* __restrict__ bq, const float* __restrict__ bk,
    const float* __restrict__ bv, _Float16* __restrict__ Qh,
    _Float16* __restrict__ Kh, _Float16* __restrict__ VT) {
  __shared__ _Float16 lds[65536];
  const int tid = threadIdx.x;
  const int bid = blockIdx.x;
  const int swz = (bid & 7) * 96 + (bid >> 3);  // XCD swizzle, 768%8==0
  const int mt = swz / 12, nt = swz % 12;
  const int sel = nt >> 2;
  const _Float16* Wsel = sel == 0 ? Wqh : (sel == 1 ? Wkh : Wvh);
  const float* bsel = sel == 0 ? bq : (sel == 1 ? bk : bv);
  const _Float16* Ab = xh + (size_t)mt * 256 * 1024;
  const _Float16* Bb = Wsel + (size_t)(nt & 3) * 256 * 1024;
  f32x4 acc[8][4] = {};
  auto ga = [&](int t, int h) { return Ab + (size_t)h * 128 * 1024 + t * 64; };
  auto gb = [&](int t, int h) { return Bb + (size_t)h * 128 * 1024 + t * 64; };
  gemm_core<1024, 1024>(ga, gb, 16, (char*)lds, tid, acc);
  const int l = tid & 63, w = tid >> 6;
  const int wm = w >> 2, wn = w & 3;
  const int lr = l & 15, lk = l >> 4;
  const int n0 = (nt & 3) * 256;
  __syncthreads();
#pragma unroll
  for (int ai = 0; ai < 8; ++ai) {
    const int rbase = wm * 128 + (ai >> 2) * 64 + (ai & 3) * 16 + lk * 4;
#pragma unroll
    for (int j = 0; j < 4; ++j) {
      const int col = wn * 64 + j * 16 + lr;
      const float bvv = bsel[n0 + col];
#pragma unroll
      for (int r = 0; r < 4; ++r) {
        const int row = rbase + r;
        const float v = acc[ai][j][r] + bvv;
        if (sel < 2)
          lds[row * 256 + ((col + (row >> 2) * 16) & 255)] = (_Float16)v;
        else
          lds[col * 256 + ((row + (col >> 2) * 16) & 255)] = (_Float16)v;
      }
    }
  }
  __syncthreads();
#pragma unroll
  for (int i = 0; i < 16; ++i) {
    const int c = i * 512 + tid;
    const int row = c >> 5, c8 = c & 31;
    half8 v = *(const half8*)&lds[row * 256 + ((c8 * 8 + (row >> 2) * 16) & 255)];
    if (sel < 2) {
      _Float16* Out = sel == 0 ? Qh : Kh;
      *(half8*)&Out[(size_t)(mt * 256 + row) * 1024 + n0 + c8 * 8] = v;
    } else {
      const int bb = mt >> 3, t0 = (mt & 7) * 256;
      *(half8*)&VT[((size_t)bb * 1024 + n0 + row) * 2048 + t0 + c8 * 8] = v;
    }
  }
}

// Causal QK^T: 576 uniform jobs, each a 256(q) x 128(k) tile, writes f16 S
// into compact tri layout [b][tri36][256][256] (half-tile per job).
__global__ __launch_bounds__(512) void gemm_qk(const _Float16* __restrict__ Qh,
                                               const _Float16* __restrict__ Kh,
                                               _Float16* __restrict__ Sc) {
  __shared__ _Float16 lds[49152];
  const int tid = threadIdx.x;
  const int j = blockIdx.x;
  const int b = j / 72, r = j % 72;
  int qt = 0, cum = 0;
  while (cum + (qt + 1) * 2 <= r) { cum += (qt + 1) * 2; ++qt; }
  const int jn = r - cum;  // 0..(qt+1)*2-1
  const _Float16* Ab = Qh + ((size_t)b * 2048 + qt * 256) * 1024;
  const _Float16* Bb = Kh + ((size_t)b * 2048 + jn * 128) * 1024;
  f32x4 acc[4][4] = {};
  auto ga = [&](int t, int h) { return Ab + (size_t)h * 128 * 1024 + t * 64; };
  auto gb = [&](int t) { return Bb + t * 64; };
  gemm_n128<1024, 1024>(ga, gb, 16, (char*)lds, tid, acc);
  const int l = tid & 63, w = tid >> 6;
  const int wm = w >> 1, wn = w & 1;
  const int lr = l & 15, lk = l >> 4;
  _Float16* St = Sc + ((size_t)b * 36 + (size_t)(qt * (qt + 1) / 2) + (jn >> 1)) * 65536 +
                 (jn & 1) * 128;
  const _Float16 NINF = (_Float16)(-__builtin_inff());
#pragma unroll
  for (int i = 0; i < 4; ++i) {
#pragma unroll
    for (int jj = 0; jj < 4; ++jj) {
      const int col = wn * 64 + jj * 16 + lr;
      const int kg = jn * 128 + col;
#pragma unroll
      for (int rr = 0; rr < 4; ++rr) {
        const int row = wm * 64 + i * 16 + lk * 4 + rr;
        const int qg = qt * 256 + row;
        St[(size_t)row * 256 + col] =
            (kg <= qg) ? (_Float16)(acc[i][jj][rr] * ATT_SCALE) : NINF;
      }
    }
  }
}

// One wave per row: softmax over f16 compact S row, writes f16 P.
__global__ __launch_bounds__(256) void softmax_p(const _Float16* __restrict__ Sc,
                                                 _Float16* __restrict__ Pc) {
  const int l = threadIdx.x & 63;
  const int gid = blockIdx.x * 4 + (threadIdx.x >> 6);
  const int b = gid >> 11, q = gid & 2047;
  const int qt = q >> 8, rq = q & 255;
  const int ntile = qt + 1;
  const size_t base = ((size_t)b * 36 + (size_t)(qt * (qt + 1) / 2)) * 65536 +
                      (size_t)rq * 256 + l * 4;
  float vx[32];
  float m = -__builtin_inff();
#pragma unroll
  for (int c = 0; c < 8; ++c) {
    float x0 = -__builtin_inff(), x1 = x0, x2 = x0, x3 = x0;
    if (c < ntile) {
      half4 t = *(const half4*)&Sc[base + (size_t)c * 65536];
      x0 = (float)t[0]; x1 = (float)t[1]; x2 = (float)t[2]; x3 = (float)t[3];
    }
    vx[4 * c] = x0; vx[4 * c + 1] = x1; vx[4 * c + 2] = x2; vx[4 * c + 3] = x3;
    m = fmaxf(m, fmaxf(fmaxf(x0, x1), fmaxf(x2, x3)));
  }
#pragma unroll
  for (int s = 1; s < 64; s <<= 1) m = fmaxf(m, __shfl_xor(m, s, 64));
  float sum = 0.f;
#pragma unroll
  for (int i = 0; i < 32; ++i) { vx[i] = __expf(vx[i] - m); sum += vx[i]; }
#pragma unroll
  for (int s = 1; s < 64; s <<= 1) sum += __shfl_xor(sum, s, 64);
  const float inv = 1.f / sum;
  _Float16* Pb = Pc + base;
#pragma unroll
  for (int c = 0; c < 8; ++c) {
    if (c < ntile) {
      half4 p;
      p[0] = (_Float16)(vx[4 * c] * inv);
      p[1] = (_Float16)(vx[4 * c + 1] * inv);
      p[2] = (_Float16)(vx[4 * c + 2] * inv);
      p[3] = (_Float16)(vx[4 * c + 3] * inv);
      *(half4*)&Pb[(size_t)c * 65536] = p;
    }
  }
}

// PV: 512 jobs (qt descending = LPT), each 256(q) x 128(d) output tile.
__global__ __launch_bounds__(512) void gemm_pv(const _Float16* __restrict__ Pc,
                                               const _Float16* __restrict__ VT,
                                               float* __restrict__ O) {
  __shared__ _Float16 lds[49152];
  const int tid = threadIdx.x;
  const int j = blockIdx.x;
  const int qt = 7 - (j >> 6);
  const int dt = (j >> 3) & 7, b = j & 7;
  const _Float16* Pb = Pc + ((size_t)b * 36 + (size_t)(qt * (qt + 1) / 2)) * 65536;
  const _Float16* Vb = VT + ((size_t)b * 1024 + dt * 128) * 2048;
  f32x4 acc[4][4] = {};
  auto ga = [&](int t, int h) {
    return Pb + (size_t)(t >> 2) * 65536 + (size_t)h * 32768 + (t & 3) * 64;
  };
  auto gb = [&](int t) { return Vb + t * 64; };
  gemm_n128<256, 2048>(ga, gb, (qt + 1) * 4, (char*)lds, tid, acc);
  const int l = tid & 63, w = tid >> 6;
  const int wm = w >> 1, wn = w & 1;
  const int lr = l & 15, lk = l >> 4;
#pragma unroll
  for (int i = 0; i < 4; ++i) {
#pragma unroll
    for (int jj = 0; jj < 4; ++jj) {
      const int cg = dt * 128 + wn * 64 + jj * 16 + lr;
#pragma unroll
      for (int rr = 0; rr < 4; ++rr) {
        const int rg = qt * 256 + wm * 64 + i * 16 + lk * 4 + rr;
        O[((size_t)b * 2048 + rg) * 1024 + cg] = acc[i][jj][rr];
      }
    }
  }
}

extern "C" void kernel_launch(void* const* d_in, const int* in_sizes, int n_in,
                              void* d_out, int out_size, void* d_ws, size_t ws_size,
                              hipStream_t stream) {
  const float* x    = (const float*)d_in[0];
  const float* Wq_w = (const float*)d_in[1];
  const float* Wq_b = (const float*)d_in[2];
  const float* Wk_w = (const float*)d_in[3];
  const float* Wk_b = (const float*)d_in[4];
  const float* Wv_w = (const float*)d_in[5];
  const float* Wv_b = (const float*)d_in[6];
  float* out = (float*)d_out;
  char* ws = (char*)d_ws;
  _Float16* xh  = (_Float16*)(ws);              // 32 MiB (dead after proj)
  _Float16* Wqh = (_Float16*)(ws + 33554432);
  _Float16* Wkh = (_Float16*)(ws + 35651584);
  _Float16* Wvh = (_Float16*)(ws + 37748736);
  _Float16* Sc  = (_Float16*)(ws);              // f16 compact tri S, 37.75 MB (aliases xh+W)
  _Float16* Qh  = (_Float16*)(ws + 75497472);   // 32 MiB
  _Float16* Kh  = (_Float16*)(ws + 109051904);  // 32 MiB
  _Float16* Pc  = (_Float16*)(ws + 75497472);   // f16 compact tri P (aliases Q/K)
  _Float16* VT  = (_Float16*)(ws + 142606336);  // 32 MiB

  cvt_all<<<2048, 256, 0, stream>>>(x, Wq_w, Wk_w, Wv_w, xh, Wqh, Wkh, Wvh);
  gemm_qkv<<<768, 512, 0, stream>>>(xh, Wqh, Wkh, Wvh, Wq_b, Wk_b, Wv_b, Qh, Kh, VT);
  gemm_qk<<<576, 512, 0, stream>>>(Qh, Kh, Sc);
  softmax_p<<<4096, 256, 0, stream>>>(Sc, Pc);
  gemm_pv<<<512, 512, 0, stream>>>(Pc, VT, out);
}

// Round 10
// 274.028 us; speedup vs baseline: 1.1717x; 1.0049x over previous
//
#include <hip/hip_runtime.h>

// ScaledAttention B=8,T=2048,D=1024 single-head, SCALE=1/8.
// cvt -> fused QKV proj (NEW 2-phase 256x256 core) -> causal QK^T (n128 core,
// f16 S) -> row softmax -> PV (n128 core, LPT). Swizzle: chunk ^= (row&7).

typedef float f32x4 __attribute__((ext_vector_type(4)));
typedef _Float16 half8 __attribute__((ext_vector_type(8)));
typedef _Float16 half4 __attribute__((ext_vector_type(4)));

#define DEVINL __device__ __forceinline__
static constexpr float ATT_SCALE = 0.125f;  // 1/sqrt(1024/16)

DEVINL void gload_lds16(const _Float16* g, _Float16* l) {
  __builtin_amdgcn_global_load_lds((const __attribute__((address_space(1))) void*)g,
                                   (__attribute__((address_space(3))) void*)l, 16, 0, 0);
}

#define SBAR() __builtin_amdgcn_sched_barrier(0)

// ----------------- 2-phase 256x256 core (qkv) ------------------------------
// 8 waves 2Mx4N, wave tile 128x64, acc[8][4] (ai = ih*4+i).
// LDS buf b @ b*65536: A-half0@0 A-half1@16384 B-half0@32768 B-half1@49152.
// Element (r, 16B-chunk c) at physical chunk c ^ (r&7).
// Per tile t: PH1 {RDB8+RDA(ih1), STGA(t+1)->obuf | bar | MMQ ih0}
//             PH2 {STGB(t+2)->bufb, vmcnt(4) | bar | MMH jh0, RDB8-slack? no:
//                  MMH jh0, MMH jh1, RDA(obuf,ih0)->aA}
// All consume waits are compiler-counted lgkmcnt(<=8); staged loads stay >=4
// in flight (vmcnt(4)) except the tail.
template <int LDA, int LDB, class GA, class GB>
DEVINL void gemm_2ph(GA ga, GB gb, int NT, char* ldsb, int tid, f32x4 acc[8][4]) {
  const int l = tid & 63, w = tid >> 6;
  const int wm = w >> 2, wn = w & 3;
  const int lr = l & 15, lk = l >> 4;
  int srow[2], scol[2];
#pragma unroll
  for (int i = 0; i < 2; ++i) {
    const int P = i * 512 + w * 64 + l;
    srow[i] = P >> 3;
    scol[i] = (P & 7) ^ (srow[i] & 7);
  }
  const int ch0 = ((lk ^ (lr & 7)) << 4);
  const int ch1 = (((lk + 4) ^ (lr & 7)) << 4);
  const int abase = lr * 128;
  const int bbase = (wn >> 1) * 16384 + (wn & 1) * 8192 + lr * 128;

  auto STGA = [&](int t, int bufb) {
#pragma unroll
    for (int h = 0; h < 2; ++h) {
      const _Float16* g0 = ga(t, h);
      char* dst = ldsb + bufb * 65536 + h * 16384;
#pragma unroll
      for (int i = 0; i < 2; ++i)
        gload_lds16(g0 + (size_t)srow[i] * LDA + scol[i] * 8,
                    (_Float16*)(dst + i * 8192 + w * 1024));
    }
  };
  auto STGB = [&](int t, int bufb) {
#pragma unroll
    for (int h = 0; h < 2; ++h) {
      const _Float16* g0 = gb(t, h);
      char* dst = ldsb + bufb * 65536 + 32768 + h * 16384;
#pragma unroll
      for (int i = 0; i < 2; ++i)
        gload_lds16(g0 + (size_t)srow[i] * LDB + scol[i] * 8,
                    (_Float16*)(dst + i * 8192 + w * 1024));
    }
  };
  half8 aA[4][2], aB[4][2], bC[4][2];
  auto RDA = [&](int bufb, int ih, half8 d[4][2]) {
    const char* sA = ldsb + bufb * 65536 + wm * 16384 + ih * 8192;
#pragma unroll
    for (int i = 0; i < 4; ++i) {
      d[i][0] = *(const half8*)(sA + abase + i * 2048 + ch0);
      d[i][1] = *(const half8*)(sA + abase + i * 2048 + ch1);
    }
  };
  auto RDB8 = [&](int bufb) {
    const char* sB = ldsb + bufb * 65536 + 32768;
#pragma unroll
    for (int j = 0; j < 4; ++j) {
      bC[j][0] = *(const half8*)(sB + bbase + j * 2048 + ch0);
      bC[j][1] = *(const half8*)(sB + bbase + j * 2048 + ch1);
    }
  };

#define MMQ() _Pragma("unroll") for (int kk_ = 0; kk_ < 2; ++kk_) \
    _Pragma("unroll") for (int i_ = 0; i_ < 4; ++i_) \
    _Pragma("unroll") for (int j_ = 0; j_ < 4; ++j_) \
      acc[i_][j_] = __builtin_amdgcn_mfma_f32_16x16x32_f16( \
          aA[i_][kk_], bC[j_][kk_], acc[i_][j_], 0, 0, 0);
#define MMH(JO) _Pragma("unroll") for (int kk_ = 0; kk_ < 2; ++kk_) \
    _Pragma("unroll") for (int i_ = 0; i_ < 4; ++i_) \
    _Pragma("unroll") for (int jj_ = 0; jj_ < 2; ++jj_) \
      acc[4 + i_][(JO) + jj_] = __builtin_amdgcn_mfma_f32_16x16x32_f16( \
          aB[i_][kk_], bC[(JO) + jj_][kk_], acc[4 + i_][(JO) + jj_], 0, 0, 0);

  // prologue: A(0),B(0)->buf0, B(1)->buf1; wait A0+B0 (leave B1 in flight)
  STGA(0, 0); STGB(0, 0); STGB(1, 1);
  asm volatile("s_waitcnt vmcnt(4)" ::: "memory");
  __builtin_amdgcn_s_barrier(); SBAR();
  RDA(0, 0, aA);

  for (int t = 0; t < NT; ++t) {
    const int bufb = t & 1, obuf = bufb ^ 1;
    // PH1
    RDB8(bufb);
    RDA(bufb, 1, aB);
    if (t + 1 < NT) STGA(t + 1, obuf);
    SBAR(); __builtin_amdgcn_s_barrier();
    __builtin_amdgcn_s_setprio(1);
    MMQ();                         // lgkm(8): waits bC(+aA older); aB drains under
    __builtin_amdgcn_s_setprio(0); SBAR();
    // PH2
    if (t + 2 < NT) {
      STGB(t + 2, bufb);
      asm volatile("s_waitcnt vmcnt(4)" ::: "memory");  // drains B(t+1)+A(t+1)
    } else {
      asm volatile("s_waitcnt vmcnt(0)" ::: "memory");
    }
    SBAR(); __builtin_amdgcn_s_barrier();
    __builtin_amdgcn_s_setprio(1);
    MMH(0);                        // aB drained during MMQ (lgkm free)
    MMH(2);
    __builtin_amdgcn_s_setprio(0);
    if (t + 1 < NT) RDA(obuf, 0, aA);  // next tile's aA; consumed via MMQ's lgkm(8)
    SBAR();
  }
#undef MMQ
#undef MMH
}

// ------------------- 256x128 core (qk, pv) ---------------------------------
template <int LDA, int LDB, class GA, class GB>
DEVINL void gemm_n128(GA ga, GB gb, int NT, char* ldsb, int tid, f32x4 acc[4][4]) {
  const int l = tid & 63, w = tid >> 6;
  const int wm = w >> 1, wn = w & 1;
  const int lr = l & 15, lk = l >> 4;
  int srow[2], scol[2];
#pragma unroll
  for (int i = 0; i < 2; ++i) {
    const int P = i * 512 + w * 64 + l;
    srow[i] = P >> 3;
    scol[i] = (P & 7) ^ (srow[i] & 7);
  }
  const int ch0 = ((lk ^ (lr & 7)) << 4);
  const int ch1 = (((lk + 4) ^ (lr & 7)) << 4);
  const int abase = (wm >> 1) * 16384 + ((wm & 1) * 64 + lr) * 128;
  const int bbase = 32768 + (wn * 64 + lr) * 128;

  auto STG = [&](const _Float16* g0, int ld, int bufb, int slot) {
    char* dst = ldsb + bufb * 49152 + slot * 16384;
#pragma unroll
    for (int i = 0; i < 2; ++i)
      gload_lds16(g0 + (size_t)srow[i] * ld + scol[i] * 8,
                  (_Float16*)(dst + i * 8192 + w * 1024));
  };
  half8 a[4][2], bfr[4][2];
  auto RD = [&](int bufb) {
    const char* bb = ldsb + bufb * 49152;
#pragma unroll
    for (int i = 0; i < 4; ++i) {
      a[i][0] = *(const half8*)(bb + abase + i * 2048 + ch0);
      a[i][1] = *(const half8*)(bb + abase + i * 2048 + ch1);
    }
#pragma unroll
    for (int j = 0; j < 4; ++j) {
      bfr[j][0] = *(const half8*)(bb + bbase + j * 2048 + ch0);
      bfr[j][1] = *(const half8*)(bb + bbase + j * 2048 + ch1);
    }
  };

  STG(ga(0, 0), LDA, 0, 0); STG(ga(0, 1), LDA, 0, 1); STG(gb(0), LDB, 0, 2);
  STG(ga(1, 0), LDA, 1, 0); STG(ga(1, 1), LDA, 1, 1); STG(gb(1), LDB, 1, 2);
  asm volatile("s_waitcnt vmcnt(6)" ::: "memory");
  __builtin_amdgcn_s_barrier();

  for (int t = 0; t < NT; ++t) {
    const int bufb = t & 1;
    RD(bufb);
    SBAR();
    __builtin_amdgcn_s_barrier();
    asm volatile("s_waitcnt lgkmcnt(0)" ::: "memory");
    SBAR();
    __builtin_amdgcn_s_setprio(1);
#pragma unroll
    for (int i = 0; i < 4; ++i)
#pragma unroll
      for (int j = 0; j < 4; ++j)
        acc[i][j] = __builtin_amdgcn_mfma_f32_16x16x32_f16(a[i][0], bfr[j][0], acc[i][j], 0, 0, 0);
    __builtin_amdgcn_s_setprio(0);
    SBAR();
    __builtin_amdgcn_s_barrier();
    if (t + 2 < NT) {
      STG(ga(t + 2, 0), LDA, bufb, 0);
      STG(ga(t + 2, 1), LDA, bufb, 1);
      STG(gb(t + 2), LDB, bufb, 2);
      asm volatile("s_waitcnt vmcnt(6)" ::: "memory");
    } else if (t + 1 < NT) {
      asm volatile("s_waitcnt vmcnt(0)" ::: "memory");
    }
    SBAR();
    __builtin_amdgcn_s_barrier();
    __builtin_amdgcn_s_setprio(1);
#pragma unroll
    for (int i = 0; i < 4; ++i)
#pragma unroll
      for (int j = 0; j < 4; ++j)
        acc[i][j] = __builtin_amdgcn_mfma_f32_16x16x32_f16(a[i][1], bfr[j][1], acc[i][j], 0, 0, 0);
    __builtin_amdgcn_s_setprio(0);
    SBAR();
    __builtin_amdgcn_s_barrier();
  }
}

// ---------------------------------------------------------------------------
__global__ __launch_bounds__(256) void cvt_all(const float* __restrict__ x,
                                               const float* __restrict__ wq,
                                               const float* __restrict__ wk,
                                               const float* __restrict__ wv,
                                               _Float16* __restrict__ xh,
                                               _Float16* __restrict__ wqh,
                                               _Float16* __restrict__ wkh,
                                               _Float16* __restrict__ wvh) {
  const int n8 = 2490368;
  for (int i = blockIdx.x * 256 + threadIdx.x; i < n8; i += 2048 * 256) {
    const float* src; _Float16* dst; int off;
    if (i < 2097152)      { src = x;  dst = xh;  off = i; }
    else if (i < 2228224) { src = wq; dst = wqh; off = i - 2097152; }
    else if (i < 2359296) { src = wk; dst = wkh; off = i - 2228224; }
    else                  { src = wv; dst = wvh; off = i - 2359296; }
    const float4* p = (const float4*)src + (size_t)off * 2;
    float4 v0 = p[0], v1 = p[1];
    half8 h;
    h[0] = (_Float16)v0.x; h[1] = (_Float16)v0.y; h[2] = (_Float16)v0.z; h[3] = (_Float16)v0.w;
    h[4] = (_Float16)v1.x; h[5] = (_Float16)v1.y; h[6] = (_Float16)v1.z; h[7] = (_Float16)v1.w;
    *((half8*)dst + off) = h;
  }
}

// Fused QKV: C[m,n]=sum_k x[m,k]W[n,k]+b[n], M=16384, N=3072, K=1024.
__global__ __launch_bounds__(512) void gemm_qkv(
    const _Float16* __restrict__ xh, const _Float16* __restrict__ Wqh,
    const _Float16* __restrict__ Wkh, const _Float16* __restrict__ Wvh,
    const float* __restrict__ bq, const float* __restrict__ bk,
    const float* __restrict__ bv, _Float16* __restrict__ Qh,
    _Float16* __restrict__ Kh, _Float16* __restrict__ VT) {
  __shared__ _Float16 lds[65536];
  const int tid = threadIdx.x;
  const int bid = blockIdx.x;
  const int swz = (bid & 7) * 96 + (bid >> 3);  // XCD swizzle, 768%8==0
  const int mt = swz / 12, nt = swz % 12;
  const int sel = nt >> 2;
  const _Float16* Wsel = sel == 0 ? Wqh : (sel == 1 ? Wkh : Wvh);
  const float* bsel = sel == 0 ? bq : (sel == 1 ? bk : bv);
  const _Float16* Ab = xh + (size_t)mt * 256 * 1024;
  const _Float16* Bb = Wsel + (size_t)(nt & 3) * 256 * 1024;
  f32x4 acc[8][4] = {};
  auto ga = [&](int t, int h) { return Ab + (size_t)h * 128 * 1024 + t * 64; };
  auto gb = [&](int t, int h) { return Bb + (size_t)h * 128 * 1024 + t * 64; };
  gemm_2ph<1024, 1024>(ga, gb, 16, (char*)lds, tid, acc);
  const int l = tid & 63, w = tid >> 6;
  const int wm = w >> 2, wn = w & 3;
  const int lr = l & 15, lk = l >> 4;
  const int n0 = (nt & 3) * 256;
  __syncthreads();
#pragma unroll
  for (int ai = 0; ai < 8; ++ai) {
    const int rbase = wm * 128 + (ai >> 2) * 64 + (ai & 3) * 16 + lk * 4;
#pragma unroll
    for (int j = 0; j < 4; ++j) {
      const int col = wn * 64 + j * 16 + lr;
      const float bvv = bsel[n0 + col];
#pragma unroll
      for (int r = 0; r < 4; ++r) {
        const int row = rbase + r;
        const float v = acc[ai][j][r] + bvv;
        if (sel < 2)
          lds[row * 256 + ((col + (row >> 2) * 16) & 255)] = (_Float16)v;
        else
          lds[col * 256 + ((row + (col >> 2) * 16) & 255)] = (_Float16)v;
      }
    }
  }
  __syncthreads();
#pragma unroll
  for (int i = 0; i < 16; ++i) {
    const int c = i * 512 + tid;
    const int row = c >> 5, c8 = c & 31;
    half8 v = *(const half8*)&lds[row * 256 + ((c8 * 8 + (row >> 2) * 16) & 255)];
    if (sel < 2) {
      _Float16* Out = sel == 0 ? Qh : Kh;
      *(half8*)&Out[(size_t)(mt * 256 + row) * 1024 + n0 + c8 * 8] = v;
    } else {
      const int bb = mt >> 3, t0 = (mt & 7) * 256;
      *(half8*)&VT[((size_t)bb * 1024 + n0 + row) * 2048 + t0 + c8 * 8] = v;
    }
  }
}

// Causal QK^T: 576 uniform 256x128 jobs -> f16 compact tri S.
__global__ __launch_bounds__(512) void gemm_qk(const _Float16* __restrict__ Qh,
                                               const _Float16* __restrict__ Kh,
                                               _Float16* __restrict__ Sc) {
  __shared__ _Float16 lds[49152];
  const int tid = threadIdx.x;
  const int j = blockIdx.x;
  const int b = j / 72, r = j % 72;
  int qt = 0, cum = 0;
  while (cum + (qt + 1) * 2 <= r) { cum += (qt + 1) * 2; ++qt; }
  const int jn = r - cum;
  const _Float16* Ab = Qh + ((size_t)b * 2048 + qt * 256) * 1024;
  const _Float16* Bb = Kh + ((size_t)b * 2048 + jn * 128) * 1024;
  f32x4 acc[4][4] = {};
  auto ga = [&](int t, int h) { return Ab + (size_t)h * 128 * 1024 + t * 64; };
  auto gb = [&](int t) { return Bb + t * 64; };
  gemm_n128<1024, 1024>(ga, gb, 16, (char*)lds, tid, acc);
  const int l = tid & 63, w = tid >> 6;
  const int wm = w >> 1, wn = w & 1;
  const int lr = l & 15, lk = l >> 4;
  _Float16* St = Sc + ((size_t)b * 36 + (size_t)(qt * (qt + 1) / 2) + (jn >> 1)) * 65536 +
                 (jn & 1) * 128;
  const _Float16 NINF = (_Float16)(-__builtin_inff());
#pragma unroll
  for (int i = 0; i < 4; ++i) {
#pragma unroll
    for (int jj = 0; jj < 4; ++jj) {
      const int col = wn * 64 + jj * 16 + lr;
      const int kg = jn * 128 + col;
#pragma unroll
      for (int rr = 0; rr < 4; ++rr) {
        const int row = wm * 64 + i * 16 + lk * 4 + rr;
        const int qg = qt * 256 + row;
        St[(size_t)row * 256 + col] =
            (kg <= qg) ? (_Float16)(acc[i][jj][rr] * ATT_SCALE) : NINF;
      }
    }
  }
}

// One wave per row: softmax over f16 compact S row, writes f16 P.
__global__ __launch_bounds__(256) void softmax_p(const _Float16* __restrict__ Sc,
                                                 _Float16* __restrict__ Pc) {
  const int l = threadIdx.x & 63;
  const int gid = blockIdx.x * 4 + (threadIdx.x >> 6);
  const int b = gid >> 11, q = gid & 2047;
  const int qt = q >> 8, rq = q & 255;
  const int ntile = qt + 1;
  const size_t base = ((size_t)b * 36 + (size_t)(qt * (qt + 1) / 2)) * 65536 +
                      (size_t)rq * 256 + l * 4;
  float vx[32];
  float m = -__builtin_inff();
#pragma unroll
  for (int c = 0; c < 8; ++c) {
    float x0 = -__builtin_inff(), x1 = x0, x2 = x0, x3 = x0;
    if (c < ntile) {
      half4 t = *(const half4*)&Sc[base + (size_t)c * 65536];
      x0 = (float)t[0]; x1 = (float)t[1]; x2 = (float)t[2]; x3 = (float)t[3];
    }
    vx[4 * c] = x0; vx[4 * c + 1] = x1; vx[4 * c + 2] = x2; vx[4 * c + 3] = x3;
    m = fmaxf(m, fmaxf(fmaxf(x0, x1), fmaxf(x2, x3)));
  }
#pragma unroll
  for (int s = 1; s < 64; s <<= 1) m = fmaxf(m, __shfl_xor(m, s, 64));
  float sum = 0.f;
#pragma unroll
  for (int i = 0; i < 32; ++i) { vx[i] = __expf(vx[i] - m); sum += vx[i]; }
#pragma unroll
  for (int s = 1; s < 64; s <<= 1) sum += __shfl_xor(sum, s, 64);
  const float inv = 1.f / sum;
  _Float16* Pb = Pc + base;
#pragma unroll
  for (int c = 0; c < 8; ++c) {
    if (c < ntile) {
      half4 p;
      p[0] = (_Float16)(vx[4 * c] * inv);
      p[1] = (_Float16)(vx[4 * c + 1] * inv);
      p[2] = (_Float16)(vx[4 * c + 2] * inv);
      p[3] = (_Float16)(vx[4 * c + 3] * inv);
      *(half4*)&Pb[(size_t)c * 65536] = p;
    }
  }
}

// PV: 512 jobs (qt descending = LPT), each 256(q) x 128(d) output tile.
__global__ __launch_bounds__(512) void gemm_pv(const _Float16* __restrict__ Pc,
                                               const _Float16* __restrict__ VT,
                                               float* __restrict__ O) {
  __shared__ _Float16 lds[49152];
  const int tid = threadIdx.x;
  const int j = blockIdx.x;
  const int qt = 7 - (j >> 6);
  const int dt = (j >> 3) & 7, b = j & 7;
  const _Float16* Pb = Pc + ((size_t)b * 36 + (size_t)(qt * (qt + 1) / 2)) * 65536;
  const _Float16* Vb = VT + ((size_t)b * 1024 + dt * 128) * 2048;
  f32x4 acc[4][4] = {};
  auto ga = [&](int t, int h) {
    return Pb + (size_t)(t >> 2) * 65536 + (size_t)h * 32768 + (t & 3) * 64;
  };
  auto gb = [&](int t) { return Vb + t * 64; };
  gemm_n128<256, 2048>(ga, gb, (qt + 1) * 4, (char*)lds, tid, acc);
  const int l = tid & 63, w = tid >> 6;
  const int wm = w >> 1, wn = w & 1;
  const int lr = l & 15, lk = l >> 4;
#pragma unroll
  for (int i = 0; i < 4; ++i) {
#pragma unroll
    for (int jj = 0; jj < 4; ++jj) {
      const int cg = dt * 128 + wn * 64 + jj * 16 + lr;
#pragma unroll
      for (int rr = 0; rr < 4; ++rr) {
        const int rg = qt * 256 + wm * 64 + i * 16 + lk * 4 + rr;
        O[((size_t)b * 2048 + rg) * 1024 + cg] = acc[i][jj][rr];
      }
    }
  }
}

extern "C" void kernel_launch(void* const* d_in, const int* in_sizes, int n_in,
                              void* d_out, int out_size, void* d_ws, size_t ws_size,
                              hipStream_t stream) {
  const float* x    = (const float*)d_in[0];
  const float* Wq_w = (const float*)d_in[1];
  const float* Wq_b = (const float*)d_in[2];
  const float* Wk_w = (const float*)d_in[3];
  const float* Wk_b = (const float*)d_in[4];
  const float* Wv_w = (const float*)d_in[5];
  const float* Wv_b = (const float*)d_in[6];
  float* out = (float*)d_out;
  char* ws = (char*)d_ws;
  _Float16* xh  = (_Float16*)(ws);              // 32 MiB (dead after proj)
  _Float16* Wqh = (_Float16*)(ws + 33554432);
  _Float16* Wkh = (_Float16*)(ws + 35651584);
  _Float16* Wvh = (_Float16*)(ws + 37748736);
  _Float16* Sc  = (_Float16*)(ws);              // f16 compact tri S (aliases xh+W)
  _Float16* Qh  = (_Float16*)(ws + 75497472);   // 32 MiB
  _Float16* Kh  = (_Float16*)(ws + 109051904);  // 32 MiB
  _Float16* Pc  = (_Float16*)(ws + 75497472);   // f16 compact tri P (aliases Q/K)
  _Float16* VT  = (_Float16*)(ws + 142606336);  // 32 MiB

  cvt_all<<<2048, 256, 0, stream>>>(x, Wq_w, Wk_w, Wv_w, xh, Wqh, Wkh, Wvh);
  gemm_qkv<<<768, 512, 0, stream>>>(xh, Wqh, Wkh, Wvh, Wq_b, Wk_b, Wv_b, Qh, Kh, VT);
  gemm_qk<<<576, 512, 0, stream>>>(Qh, Kh, Sc);
  softmax_p<<<4096, 256, 0, stream>>>(Sc, Pc);
  gemm_pv<<<512, 512, 0, stream>>>(Pc, VT, out);
}